// Round 8
// baseline (7058.286 us; speedup 1.0000x reference)
//
#include <hip/hip_runtime.h>
#include <math.h>

// ---------- types / helpers ----------
using bf16x8 = __attribute__((ext_vector_type(8))) short;
using f32x4  = __attribute__((ext_vector_type(4))) float;
using u32x2  = __attribute__((ext_vector_type(2))) unsigned int;
using u32x4  = __attribute__((ext_vector_type(4))) unsigned int;
typedef unsigned short u16;
typedef unsigned int   u32;

#define EPSBN 1e-3f

__device__ __forceinline__ u16 f2bf(float f){
  union { float f; u32 u; } c; c.f = f;
  u32 u = c.u + 0x7fffu + ((c.u >> 16) & 1u);
  return (u16)(u >> 16);
}
__device__ __forceinline__ float bf2f(u16 b){
  union { u32 u; float f; } c; c.u = ((u32)b) << 16; return c.f;
}
__device__ __forceinline__ void splitstore(float v, u16* ph, u16* pl){
  u16 h = f2bf(v); *ph = h; *pl = f2bf(v - bf2f(h));
}
__device__ __forceinline__ f32x4 MFMA(bf16x8 a, bf16x8 b, f32x4 c){
  return __builtin_amdgcn_mfma_f32_16x16x32_bf16(a, b, c, 0, 0, 0);
}

// coherent-point (cross-XCD visible) accesses: sc0 sc1 bypass L1/L2, hit IF$.
__device__ __forceinline__ u32x4 ldq_sys(const u32* p){
  u32x4 r;
  asm volatile("global_load_dwordx4 %0, %1, off sc0 sc1" : "=v"(r) : "v"(p) : "memory");
  return r;
}
// single-transaction 8B store: payload word + epoch word become visible atomically
__device__ __forceinline__ void st64_sys(u32* p, u32 w0, u32 w1){
  u32x2 v; v.x = w0; v.y = w1;
  asm volatile("global_store_dwordx2 %0, %1, off sc0 sc1" :: "v"(p), "v"(v) : "memory");
}

// ---------- prep kernels (BN folding, transpose, bf16 hi/lo split) ----------
__global__ __launch_bounds__(256) void k_bn1_split(
    const float* __restrict__ x, const float* __restrict__ g, const float* __restrict__ b,
    const float* __restrict__ m, const float* __restrict__ v,
    u16* __restrict__ oh, u16* __restrict__ ol)
{
  int i = blockIdx.x*256 + threadIdx.x;
  if (i >= 2048000) return;
  int ci = i % 80;
  float s = g[ci] * rsqrtf(v[ci] + EPSBN);
  float val = (x[i] - m[ci]) * s + b[ci];
  splitstore(val, oh+i, ol+i);
}

// conv1 weights -> [co][kf], kf = kw*80+ci, padded K 400->416 with zeros
__global__ __launch_bounds__(256) void k_prep_c1w(
    const float* __restrict__ w0, u16* __restrict__ oh, u16* __restrict__ ol)
{
  int i = blockIdx.x*256 + threadIdx.x;
  if (i >= 512*416) return;
  int co = i / 416, kf = i - co*416;
  float val = 0.f;
  if (kf < 400){ int kw = kf/80, ci = kf - kw*80; val = w0[(kw*80+ci)*512 + co]; }
  splitstore(val, oh+i, ol+i);
}

// conv2 weights -> [co][kf], kf = kw*512+ci  (K=2560)
__global__ __launch_bounds__(256) void k_prep_c2w(
    const float* __restrict__ w1, u16* __restrict__ oh, u16* __restrict__ ol)
{
  int i = blockIdx.x*256 + threadIdx.x;
  if (i >= 5*512*512) return;
  int co = i & 511, ci = (i >> 9) & 511, kw = i >> 18;
  long o = (long)co*2560 + kw*512 + ci;
  splitstore(w1[i], oh+o, ol+o);
}

// gru Wx -> [l*2+d][n][k], BN2 scale folded into layer-0 rows
__global__ __launch_bounds__(256) void k_prep_wx(
    const float* __restrict__ wx, const float* __restrict__ g2, const float* __restrict__ v2,
    u16* __restrict__ oh, u16* __restrict__ ol)
{
  long i = (long)blockIdx.x*256 + threadIdx.x;
  if (i >= 6L*512*1536) return;
  int n = (int)(i % 1536); long r2 = i / 1536; int k = (int)(r2 % 512); int ld = (int)(r2 / 512);
  float s = (ld < 2) ? g2[k]*rsqrtf(v2[k]+EPSBN) : 1.f;
  long o = ((long)ld*1536 + n)*512 + k;
  splitstore(wx[i]*s, oh+o, ol+o);
}

__global__ __launch_bounds__(256) void k_prep_wh(
    const float* __restrict__ wh, u16* __restrict__ oh, u16* __restrict__ ol)
{
  long i = (long)blockIdx.x*256 + threadIdx.x;
  if (i >= 6L*512*1536) return;
  int n = (int)(i % 1536); long r2 = i / 1536; int k = (int)(r2 % 512); int ld = (int)(r2 / 512);
  long o = ((long)ld*1536 + n)*512 + k;
  splitstore(wh[i], oh+o, ol+o);
}

// gru biases: xbias[ld][n] = input bias (+ t2 @ Wx for layer 0), hbias = recurrent bias
__global__ __launch_bounds__(256) void k_prep_grub(
    const float* __restrict__ gb, const float* __restrict__ wx,
    const float* __restrict__ g2, const float* __restrict__ b2,
    const float* __restrict__ m2, const float* __restrict__ v2,
    float* __restrict__ xbias, float* __restrict__ hbias)
{
  int i = blockIdx.x*256 + threadIdx.x;
  if (i >= 6*1536) return;
  int n = i % 1536, ld = i / 1536;
  float xv = gb[(ld*2 + 0)*1536 + n];
  float hv = gb[(ld*2 + 1)*1536 + n];
  if (ld < 2){
    float acc = 0.f;
    for (int k = 0; k < 512; ++k){
      float s = g2[k]*rsqrtf(v2[k]+EPSBN);
      float t = b2[k] - m2[k]*s;
      acc += t * wx[((long)ld*512 + k)*1536 + n];
    }
    xv += acc;
  }
  xbias[i] = xv; hbias[i] = hv;
}

// fc weights with BN3 fold -> [n][k]
__global__ __launch_bounds__(256) void k_prep_fcw(
    const float* __restrict__ fw, const float* __restrict__ g3, const float* __restrict__ v3,
    u16* __restrict__ oh, u16* __restrict__ ol)
{
  int i = blockIdx.x*256 + threadIdx.x;
  if (i >= 512*512) return;
  int n = i & 511, k = i >> 9;
  float s = g3[k]*rsqrtf(v3[k]+EPSBN);
  long o = (long)n*512 + k;
  splitstore(fw[i]*s, oh+o, ol+o);
}

__global__ __launch_bounds__(256) void k_prep_fcb(
    const float* __restrict__ fw, const float* __restrict__ fb,
    const float* __restrict__ g3, const float* __restrict__ b3,
    const float* __restrict__ m3, const float* __restrict__ v3,
    float* __restrict__ ob)
{
  int n = blockIdx.x*256 + threadIdx.x;
  if (n >= 512) return;
  float acc = fb[n];
  for (int k = 0; k < 512; ++k){
    float s = g3[k]*rsqrtf(v3[k]+EPSBN);
    float t = b3[k] - m3[k]*s;
    acc += t * fw[k*512 + n];
  }
  ob[n] = acc;
}

__global__ __launch_bounds__(256) void k_prep_smw(
    const float* __restrict__ sw, u16* __restrict__ oh, u16* __restrict__ ol)
{
  long i = (long)blockIdx.x*256 + threadIdx.x;
  if (i >= 512L*6000) return;
  int n = (int)(i % 6000); int k = (int)(i / 6000);
  long o = (long)n*512 + k;
  splitstore(sw[i], oh+o, ol+o);
}

__global__ __launch_bounds__(256) void k_sumsplit(
    const float* __restrict__ a, const float* __restrict__ b,
    u16* __restrict__ oh, u16* __restrict__ ol)
{
  int i = blockIdx.x*256 + threadIdx.x;
  if (i >= 6352*512) return;
  splitstore(a[i] + b[i], oh+i, ol+i);
}

// ---------- split-bf16 GEMM: C[M,N] = A[M,K(hi/lo)] @ Bt[N,K(hi/lo)] + bias ----------
// AMODE 0: direct A[m][k].  AMODE 1: conv gather CW=80.  AMODE 2: conv gather CW=512.
// EPI 0: f32 out. EPI 1: relu -> split out. EPI 2: clip(0,20) -> split out.
template<int AMODE, int EPI>
__global__ __launch_bounds__(256,1)
void gemm_split(const u16* __restrict__ Ah, const u16* __restrict__ Al,
                const u16* __restrict__ Bh, const u16* __restrict__ Bl,
                const float* __restrict__ bias,
                float* __restrict__ outF, u16* __restrict__ outH, u16* __restrict__ outL,
                int M, int N, int K, int Kvalid, int TIN, int TOUT)
{
  constexpr int CW = (AMODE==1) ? 80 : 512;
  const int tid  = threadIdx.x;
  const int lane = tid & 63;
  const int w    = tid >> 6;
  const int wm = w >> 1, wn = w & 1;
  const int r  = lane & 15, kg = lane >> 4;
  const int m0 = blockIdx.y * 64 + wm * 32;
  const int n0 = blockIdx.x * 64 + wn * 32;

  long abase[2];
  #pragma unroll
  for (int mt = 0; mt < 2; ++mt){
    int m = m0 + mt*16 + r;
    int mc = m < M ? m : M - 1;
    if (AMODE == 0) abase[mt] = (long)mc * K;
    else { int bb = mc / TOUT; int tt = mc - bb * TOUT; abase[mt] = ((long)bb * TIN + 2*tt) * CW; }
  }
  long bbase[2];
  #pragma unroll
  for (int nt = 0; nt < 2; ++nt){
    int n = n0 + nt*16 + r;
    int nc = n < N ? n : N - 1;
    bbase[nt] = (long)nc * K;
  }

  f32x4 acc[2][2];
  #pragma unroll
  for (int a_ = 0; a_ < 2; ++a_)
    #pragma unroll
    for (int b_ = 0; b_ < 2; ++b_) acc[a_][b_] = f32x4{0.f,0.f,0.f,0.f};

  const bf16x8 zfrag = {0,0,0,0,0,0,0,0};
  const int koff = kg * 8;
  const int KT = K >> 5;
  for (int kt = 0; kt < KT; ++kt){
    int kf = kt*32 + koff;
    bf16x8 ah[2], al[2], bh[2], bl[2];
    #pragma unroll
    for (int nt = 0; nt < 2; ++nt){
      bh[nt] = *(const bf16x8*)(Bh + bbase[nt] + kf);
      bl[nt] = *(const bf16x8*)(Bl + bbase[nt] + kf);
    }
    #pragma unroll
    for (int mt = 0; mt < 2; ++mt){
      if (AMODE == 0){
        long ao = abase[mt] + kf;
        ah[mt] = *(const bf16x8*)(Ah + ao); al[mt] = *(const bf16x8*)(Al + ao);
      } else {
        if (kf < Kvalid){
          int kw = kf / CW; int ci = kf - kw*CW;
          long ao = abase[mt] + (long)kw*CW + ci;
          ah[mt] = *(const bf16x8*)(Ah + ao); al[mt] = *(const bf16x8*)(Al + ao);
        } else { ah[mt] = zfrag; al[mt] = zfrag; }
      }
    }
    #pragma unroll
    for (int mt = 0; mt < 2; ++mt)
      #pragma unroll
      for (int nt = 0; nt < 2; ++nt){
        acc[mt][nt] = MFMA(ah[mt], bh[nt], acc[mt][nt]);
        acc[mt][nt] = MFMA(ah[mt], bl[nt], acc[mt][nt]);
        acc[mt][nt] = MFMA(al[mt], bh[nt], acc[mt][nt]);
      }
  }

  #pragma unroll
  for (int nt = 0; nt < 2; ++nt){
    int n = n0 + nt*16 + r;
    if (n >= N) continue;
    float bv = bias ? bias[n] : 0.f;
    #pragma unroll
    for (int mt = 0; mt < 2; ++mt){
      #pragma unroll
      for (int q = 0; q < 4; ++q){
        int m = m0 + mt*16 + kg*4 + q;
        if (m >= M) continue;
        float v = acc[mt][nt][q] + bv;
        if (EPI == 1) v = fmaxf(v, 0.f);
        if (EPI == 2) v = fminf(fmaxf(v, 0.f), 20.f);
        long o = (long)m * N + n;
        if (EPI == 0) outF[o] = v;
        else { u16 h = f2bf(v); outH[o] = h; outL[o] = f2bf(v - bf2f(h)); }
      }
    }
  }
}

// ---------- persistent bidirectional GRU layer ----------
// 64 blocks: dir = bx>>5, slice s = bx&31 (16 h-cols each) — R5's proven geometry.
// NEW exchange protocol (R8): epoch fused into the h data. Each h column is one
// aligned 8B dwordx2 {(hi<<16)|lo, epoch=t+1} at system scope — single-transaction
// visibility. Consumers poll THEIR OWN h loads until all embedded epochs == t;
// when the poll passes the data is already in registers. No producer-side drain,
// no separate flag line, no release barrier: ~3.5 coherent RTs/step -> ~1.5.
// Lap safety: advancing to store h(t+2) (overwrites h(t)'s buffer) requires having
// seen epoch t+1 on ALL columns, which implies every block finished reading h(t).
__global__ __launch_bounds__(256,1)
void gru_layer(const float* __restrict__ xp,     // [2][6352][1536]
               const u16* __restrict__ WhH, const u16* __restrict__ WhL, // [2][1536][512]
               const float* __restrict__ hbias,  // [2][1536]
               float* __restrict__ yf, float* __restrict__ yb, // [6352][512] each
               u32* __restrict__ hq_)            // [2 dirs][2 bufs][16][512][2] u32
{
  const int dir = blockIdx.x >> 5;
  const int s   = blockIdx.x & 31;
  const int tid = threadIdx.x, lane = tid & 63, w = tid >> 6;
  const int r = lane & 15, kg = lane >> 4;

  const float* xpd = xp + (long)dir * (6352L*1536);
  const u16* whh = WhH + (long)dir * (1536L*512);
  const u16* whl = WhL + (long)dir * (1536L*512);
  const float* hb = hbias + dir * 1536;
  float* y = dir ? yb : yf;
  u32* hq = hq_ + dir * 32768;

  __shared__ float red[2][4][3][64][4];   // ping-pong -> one barrier per step

  // persistent Wh fragments: wave w covers ktiles 4w..4w+3; gates g=0..2
  bf16x8 Bh[3][4], Bl[3][4];
  #pragma unroll
  for (int g = 0; g < 3; ++g){
    long nb = (long)(g*512 + s*16 + r) * 512;
    #pragma unroll
    for (int kk = 0; kk < 4; ++kk){
      int k = (w*4 + kk)*32 + kg*8;
      Bh[g][kk] = *(const bf16x8*)(whh + nb + k);
      Bl[g][kk] = *(const bf16x8*)(whl + nb + k);
    }
  }

  const int gb = tid >> 4, gj = tid & 15;
  const int gcol = s*16 + gj;
  const float bz = hb[gcol], br = hb[512 + gcol], bhh = hb[1024 + gcol];
  const int rl = ((gb >> 2) << 4) | gj;  // lane holding our (row=gb,col=gj)
  const int rq = gb & 3;
  const int cb0 = r * 512 + kg * 8;      // this lane's (row, col-group) in h image
  float hreg = 0.f;

  for (int t = 0; t < 397; ++t){
    const int tpos = dir ? (396 - t) : t;
    const long xb_ = ((long)gb*397 + tpos)*1536 + gcol;
    float xz = xpd[xb_], xr = xpd[xb_ + 512], xh = xpd[xb_ + 1024];

    f32x4 a0 = f32x4{0.f,0.f,0.f,0.f}, a1 = a0, a2 = a0;
    if (t > 0){
      const u32 tt = (u32)t;
      const u32* hqb = hq + (t & 1) * 16384;
      const u32* pk[4];
      #pragma unroll
      for (int kk = 0; kk < 4; ++kk)
        pk[kk] = hqb + ((cb0 + (w*4 + kk)*32) << 1);

      u32x4 q[4][4];
      for (;;){
        #pragma unroll
        for (int kk = 0; kk < 4; ++kk)
          #pragma unroll
          for (int j = 0; j < 4; ++j)
            q[kk][j] = ldq_sys(pk[kk] + j*4);
        asm volatile("s_waitcnt vmcnt(0)" ::: "memory");
        u32 bad = 0;
        #pragma unroll
        for (int kk = 0; kk < 4; ++kk)
          #pragma unroll
          for (int j = 0; j < 4; ++j)
            bad |= (q[kk][j].y ^ tt) | (q[kk][j].w ^ tt);
        if (__all(bad == 0)) break;
      }
      __builtin_amdgcn_sched_barrier(0);

      // repack {(hi<<16)|lo} pairs -> hi-plane / lo-plane bf16x8 fragments
      bf16x8 ah[4], al[4];
      #pragma unroll
      for (int kk = 0; kk < 4; ++kk){
        union { bf16x8 v; u32 u[4]; } A, L;
        #pragma unroll
        for (int j = 0; j < 4; ++j){
          A.u[j] = __builtin_amdgcn_perm(q[kk][j].z, q[kk][j].x, 0x07060302u); // hi0,hi1
          L.u[j] = __builtin_amdgcn_perm(q[kk][j].z, q[kk][j].x, 0x05040100u); // lo0,lo1
        }
        ah[kk] = A.v; al[kk] = L.v;
      }
      #pragma unroll
      for (int kk = 0; kk < 4; ++kk){
        a0 = MFMA(ah[kk], Bh[0][kk], a0); a0 = MFMA(ah[kk], Bl[0][kk], a0); a0 = MFMA(al[kk], Bh[0][kk], a0);
        a1 = MFMA(ah[kk], Bh[1][kk], a1); a1 = MFMA(ah[kk], Bl[1][kk], a1); a1 = MFMA(al[kk], Bh[1][kk], a1);
        a2 = MFMA(ah[kk], Bh[2][kk], a2); a2 = MFMA(ah[kk], Bl[2][kk], a2); a2 = MFMA(al[kk], Bh[2][kk], a2);
      }
    }
    const int tb = t & 1;
    *(f32x4*)&red[tb][w][0][lane][0] = a0;
    *(f32x4*)&red[tb][w][1][lane][0] = a1;
    *(f32x4*)&red[tb][w][2][lane][0] = a2;
    __syncthreads();
    float rz = bz, rr = br, rh = bhh;
    #pragma unroll
    for (int ww = 0; ww < 4; ++ww){
      rz += red[tb][ww][0][rl][rq];
      rr += red[tb][ww][1][rl][rq];
      rh += red[tb][ww][2][rl][rq];
    }
    float z  = 1.f / (1.f + __expf(-(xz + rz)));
    float rg = 1.f / (1.f + __expf(-(xr + rr)));
    float hh = fmaxf(xh + rg * rh, 0.f);
    hreg = z * hreg + (1.f - z) * hh;

    // fire-and-forget self-validating h store (payload + epoch, one 8B transaction)
    {
      u32* o = hq + ((t+1) & 1) * 16384 + ((gb*512 + gcol) << 1);
      u16 hi = f2bf(hreg); u16 lo = f2bf(hreg - bf2f(hi));
      st64_sys(o, ((u32)hi << 16) | (u32)lo, (u32)(t + 1));
    }
    y[((long)gb*397 + tpos)*512 + gcol] = hreg;  // off critical path
  }
}

// ---------- in-place row softmax on d_out [6352][6000] ----------
__global__ __launch_bounds__(256,1) void k_softmax(float* __restrict__ out)
{
  const int tid = threadIdx.x;
  float* prow = out + (long)blockIdx.x * 6000;
  float vals[24];
  float mx = -3.0e38f;
  #pragma unroll
  for (int i = 0; i < 24; ++i){
    int idx = tid + i*256;
    vals[i] = (idx < 6000) ? prow[idx] : -3.0e38f;
    mx = fmaxf(mx, vals[i]);
  }
  #pragma unroll
  for (int o = 32; o; o >>= 1) mx = fmaxf(mx, __shfl_xor(mx, o));
  __shared__ float sred[4];
  if ((tid & 63) == 0) sred[tid >> 6] = mx;
  __syncthreads();
  mx = fmaxf(fmaxf(sred[0], sred[1]), fmaxf(sred[2], sred[3]));
  __syncthreads();
  float sum = 0.f;
  #pragma unroll
  for (int i = 0; i < 24; ++i){
    int idx = tid + i*256;
    vals[i] = (idx < 6000) ? expf(vals[i] - mx) : 0.f;
    sum += vals[i];
  }
  #pragma unroll
  for (int o = 32; o; o >>= 1) sum += __shfl_xor(sum, o);
  if ((tid & 63) == 0) sred[tid >> 6] = sum;
  __syncthreads();
  sum = sred[0] + sred[1] + sred[2] + sred[3];
  float inv = 1.f / sum;
  #pragma unroll
  for (int i = 0; i < 24; ++i){
    int idx = tid + i*256;
    if (idx < 6000) prow[idx] = vals[i] * inv;
  }
}

// ---------- host ----------
extern "C" void kernel_launch(void* const* d_in, const int* in_sizes, int n_in,
                              void* d_out, int out_size, void* d_ws, size_t ws_size,
                              hipStream_t stream)
{
  (void)in_sizes; (void)n_in; (void)out_size; (void)ws_size;
  const float* x    = (const float*)d_in[0];
  const float* bn1g = (const float*)d_in[1];
  const float* bn1b = (const float*)d_in[2];
  const float* bn1m = (const float*)d_in[3];
  const float* bn1v = (const float*)d_in[4];
  const float* cw0  = (const float*)d_in[5];
  const float* cb0  = (const float*)d_in[6];
  const float* cw1  = (const float*)d_in[7];
  const float* cb1  = (const float*)d_in[8];
  const float* bn2g = (const float*)d_in[9];
  const float* bn2b = (const float*)d_in[10];
  const float* bn2m = (const float*)d_in[11];
  const float* bn2v = (const float*)d_in[12];
  const float* gwx  = (const float*)d_in[13];
  const float* gwh  = (const float*)d_in[14];
  const float* gbia = (const float*)d_in[15];
  const float* bn3g = (const float*)d_in[16];
  const float* bn3b = (const float*)d_in[17];
  const float* bn3m = (const float*)d_in[18];
  const float* bn3v = (const float*)d_in[19];
  const float* fcw  = (const float*)d_in[20];
  const float* fcb  = (const float*)d_in[21];
  const float* smw  = (const float*)d_in[22];
  const float* smb  = (const float*)d_in[23];

  char* p = (char*)d_ws;
  auto alloc = [&](size_t bytes)->char*{
    char* q = p; p += (bytes + 255) & ~(size_t)255; return q;
  };
  const size_t NX=2048000, NC1W=512*416, NC1O=12768L*512, NC2W=512*2560,
               NC2O=6352L*512, NWX=6L*1536*512, NXP=2L*6352*1536,
               NSMW=6000L*512, NFCW=512*512;

  u16 *xbnH=(u16*)alloc(NX*2),  *xbnL=(u16*)alloc(NX*2);
  u16 *c1wH=(u16*)alloc(NC1W*2),*c1wL=(u16*)alloc(NC1W*2);
  u16 *c1oH=(u16*)alloc(NC1O*2),*c1oL=(u16*)alloc(NC1O*2);
  u16 *c2wH=(u16*)alloc(NC2W*2),*c2wL=(u16*)alloc(NC2W*2);
  u16 *c2oH=(u16*)alloc(NC2O*2),*c2oL=(u16*)alloc(NC2O*2);
  u16 *wxH=(u16*)alloc(NWX*2),  *wxL=(u16*)alloc(NWX*2);
  u16 *whH=(u16*)alloc(NWX*2),  *whL=(u16*)alloc(NWX*2);
  float *xbias=(float*)alloc(6*1536*4), *hbias=(float*)alloc(6*1536*4);
  float *xp=(float*)alloc(NXP*4);
  float *yf=(float*)alloc(NC2O*4), *yb=(float*)alloc(NC2O*4);
  u16 *ysH=(u16*)alloc(NC2O*2), *ysL=(u16*)alloc(NC2O*2);
  u16 *fcwH=(u16*)alloc(NFCW*2),*fcwL=(u16*)alloc(NFCW*2);
  float *fcb2=(float*)alloc(512*4);
  u16 *fcoH=(u16*)alloc(NC2O*2),*fcoL=(u16*)alloc(NC2O*2);
  u16 *smwH=(u16*)alloc(NSMW*2),*smwL=(u16*)alloc(NSMW*2);
  u32 *hq=(u32*)alloc(2L*2*16*512*2*4);  // epoch-fused h exchange, 256 KB
  // no flag buffer, no memset: stale/poisoned epochs never match the fresh
  // target sequence (1..397 vs 0xAAAAAAAA / last layer's {396,397} at t<=2)

  k_bn1_split<<<8000,256,0,stream>>>(x, bn1g,bn1b,bn1m,bn1v, xbnH,xbnL);
  k_prep_c1w <<<832,256,0,stream>>>(cw0, c1wH,c1wL);
  k_prep_c2w <<<5120,256,0,stream>>>(cw1, c2wH,c2wL);
  k_prep_wx  <<<18432,256,0,stream>>>(gwx, bn2g,bn2v, wxH,wxL);
  k_prep_wh  <<<18432,256,0,stream>>>(gwh, whH,whL);
  k_prep_grub<<<36,256,0,stream>>>(gbia, gwx, bn2g,bn2b,bn2m,bn2v, xbias,hbias);
  k_prep_fcw <<<1024,256,0,stream>>>(fcw, bn3g,bn3v, fcwH,fcwL);
  k_prep_fcb <<<2,256,0,stream>>>(fcw,fcb, bn3g,bn3b,bn3m,bn3v, fcb2);
  k_prep_smw <<<12000,256,0,stream>>>(smw, smwH,smwL);

  // conv1: M=12768, N=512, K=416 (valid 400), stride2 gather from xbn [16*1600][80]
  gemm_split<1,1><<<dim3(8,200),256,0,stream>>>(xbnH,xbnL, c1wH,c1wL, cb0,
      nullptr, c1oH,c1oL, 12768,512,416, 400, 1600,798);
  // conv2: M=6352, N=512, K=2560, gather from c1o [12768][512]
  gemm_split<2,1><<<dim3(8,100),256,0,stream>>>(c1oH,c1oL, c2wH,c2wL, cb1,
      nullptr, c2oH,c2oL, 6352,512,2560, 2560, 798,397);

  const u16 *aH = c2oH, *aL = c2oL;
  for (int l = 0; l < 3; ++l){
    for (int d = 0; d < 2; ++d){
      gemm_split<0,0><<<dim3(24,100),256,0,stream>>>(aH,aL,
          wxH + (size_t)(l*2+d)*786432, wxL + (size_t)(l*2+d)*786432,
          xbias + (l*2+d)*1536,
          xp + (size_t)d*9756672, nullptr,nullptr,
          6352,1536,512, 512, 0,0);
    }
    gru_layer<<<64,256,0,stream>>>(xp,
        whH + (size_t)l*2*786432, whL + (size_t)l*2*786432,
        hbias + l*2*1536, yf,yb, hq);
    k_sumsplit<<<12704,256,0,stream>>>(yf,yb, ysH,ysL);
    aH = ysH; aL = ysL;
  }

  // fc: clip(relu(x@W+b),20) -> split
  gemm_split<0,2><<<dim3(8,100),256,0,stream>>>(ysH,ysL, fcwH,fcwL, fcb2,
      nullptr, fcoH,fcoL, 6352,512,512, 512, 0,0);
  // logits -> d_out (f32), then in-place softmax
  gemm_split<0,0><<<dim3(94,100),256,0,stream>>>(fcoH,fcoL, smwH,smwL, smb,
      (float*)d_out, nullptr,nullptr, 6352,6000,512, 512, 0,0);
  k_softmax<<<6352,256,0,stream>>>((float*)d_out);
}

// Round 9
// 6812.666 us; speedup vs baseline: 1.0361x; 1.0361x over previous
//
#include <hip/hip_runtime.h>
#include <math.h>

// ---------- types / helpers ----------
using bf16x8 = __attribute__((ext_vector_type(8))) short;
using f32x4  = __attribute__((ext_vector_type(4))) float;
using u32x2  = __attribute__((ext_vector_type(2))) unsigned int;
using u32x4  = __attribute__((ext_vector_type(4))) unsigned int;
typedef unsigned short u16;
typedef unsigned int   u32;

#define EPSBN 1e-3f

__device__ __forceinline__ u16 f2bf(float f){
  union { float f; u32 u; } c; c.f = f;
  u32 u = c.u + 0x7fffu + ((c.u >> 16) & 1u);
  return (u16)(u >> 16);
}
__device__ __forceinline__ float bf2f(u16 b){
  union { u32 u; float f; } c; c.u = ((u32)b) << 16; return c.f;
}
__device__ __forceinline__ void splitstore(float v, u16* ph, u16* pl){
  u16 h = f2bf(v); *ph = h; *pl = f2bf(v - bf2f(h));
}
__device__ __forceinline__ f32x4 MFMA(bf16x8 a, bf16x8 b, f32x4 c){
  return __builtin_amdgcn_mfma_f32_16x16x32_bf16(a, b, c, 0, 0, 0);
}

// coherent-point (cross-XCD visible) accesses: sc0 sc1 bypass L1/L2, hit IF$.
__device__ __forceinline__ u32x4 ldq_sys(const u32* p){
  u32x4 r;
  asm volatile("global_load_dwordx4 %0, %1, off sc0 sc1" : "=v"(r) : "v"(p) : "memory");
  return r;
}
// single-transaction 8B store: payload word + epoch word become visible atomically
__device__ __forceinline__ void st64_sys(u32* p, u32 w0, u32 w1){
  u32x2 v; v.x = w0; v.y = w1;
  asm volatile("global_store_dwordx2 %0, %1, off sc0 sc1" :: "v"(p), "v"(v) : "memory");
}

// ---------- prep kernels (BN folding, transpose, bf16 hi/lo split) ----------
__global__ __launch_bounds__(256) void k_bn1_split(
    const float* __restrict__ x, const float* __restrict__ g, const float* __restrict__ b,
    const float* __restrict__ m, const float* __restrict__ v,
    u16* __restrict__ oh, u16* __restrict__ ol)
{
  int i = blockIdx.x*256 + threadIdx.x;
  if (i >= 2048000) return;
  int ci = i % 80;
  float s = g[ci] * rsqrtf(v[ci] + EPSBN);
  float val = (x[i] - m[ci]) * s + b[ci];
  splitstore(val, oh+i, ol+i);
}

// conv1 weights -> [co][kf], kf = kw*80+ci, padded K 400->416 with zeros
__global__ __launch_bounds__(256) void k_prep_c1w(
    const float* __restrict__ w0, u16* __restrict__ oh, u16* __restrict__ ol)
{
  int i = blockIdx.x*256 + threadIdx.x;
  if (i >= 512*416) return;
  int co = i / 416, kf = i - co*416;
  float val = 0.f;
  if (kf < 400){ int kw = kf/80, ci = kf - kw*80; val = w0[(kw*80+ci)*512 + co]; }
  splitstore(val, oh+i, ol+i);
}

// conv2 weights -> [co][kf], kf = kw*512+ci  (K=2560)
__global__ __launch_bounds__(256) void k_prep_c2w(
    const float* __restrict__ w1, u16* __restrict__ oh, u16* __restrict__ ol)
{
  int i = blockIdx.x*256 + threadIdx.x;
  if (i >= 5*512*512) return;
  int co = i & 511, ci = (i >> 9) & 511, kw = i >> 18;
  long o = (long)co*2560 + kw*512 + ci;
  splitstore(w1[i], oh+o, ol+o);
}

// gru Wx -> [l*2+d][n][k], BN2 scale folded into layer-0 rows
__global__ __launch_bounds__(256) void k_prep_wx(
    const float* __restrict__ wx, const float* __restrict__ g2, const float* __restrict__ v2,
    u16* __restrict__ oh, u16* __restrict__ ol)
{
  long i = (long)blockIdx.x*256 + threadIdx.x;
  if (i >= 6L*512*1536) return;
  int n = (int)(i % 1536); long r2 = i / 1536; int k = (int)(r2 % 512); int ld = (int)(r2 / 512);
  float s = (ld < 2) ? g2[k]*rsqrtf(v2[k]+EPSBN) : 1.f;
  long o = ((long)ld*1536 + n)*512 + k;
  splitstore(wx[i]*s, oh+o, ol+o);
}

__global__ __launch_bounds__(256) void k_prep_wh(
    const float* __restrict__ wh, u16* __restrict__ oh, u16* __restrict__ ol)
{
  long i = (long)blockIdx.x*256 + threadIdx.x;
  if (i >= 6L*512*1536) return;
  int n = (int)(i % 1536); long r2 = i / 1536; int k = (int)(r2 % 512); int ld = (int)(r2 / 512);
  long o = ((long)ld*1536 + n)*512 + k;
  splitstore(wh[i], oh+o, ol+o);
}

// gru biases: xbias[ld][n] = input bias (+ t2 @ Wx for layer 0), hbias = recurrent bias
__global__ __launch_bounds__(256) void k_prep_grub(
    const float* __restrict__ gb, const float* __restrict__ wx,
    const float* __restrict__ g2, const float* __restrict__ b2,
    const float* __restrict__ m2, const float* __restrict__ v2,
    float* __restrict__ xbias, float* __restrict__ hbias)
{
  int i = blockIdx.x*256 + threadIdx.x;
  if (i >= 6*1536) return;
  int n = i % 1536, ld = i / 1536;
  float xv = gb[(ld*2 + 0)*1536 + n];
  float hv = gb[(ld*2 + 1)*1536 + n];
  if (ld < 2){
    float acc = 0.f;
    for (int k = 0; k < 512; ++k){
      float s = g2[k]*rsqrtf(v2[k]+EPSBN);
      float t = b2[k] - m2[k]*s;
      acc += t * wx[((long)ld*512 + k)*1536 + n];
    }
    xv += acc;
  }
  xbias[i] = xv; hbias[i] = hv;
}

// fc weights with BN3 fold -> [n][k]
__global__ __launch_bounds__(256) void k_prep_fcw(
    const float* __restrict__ fw, const float* __restrict__ g3, const float* __restrict__ v3,
    u16* __restrict__ oh, u16* __restrict__ ol)
{
  int i = blockIdx.x*256 + threadIdx.x;
  if (i >= 512*512) return;
  int n = i & 511, k = i >> 9;
  float s = g3[k]*rsqrtf(v3[k]+EPSBN);
  long o = (long)n*512 + k;
  splitstore(fw[i]*s, oh+o, ol+o);
}

__global__ __launch_bounds__(256) void k_prep_fcb(
    const float* __restrict__ fw, const float* __restrict__ fb,
    const float* __restrict__ g3, const float* __restrict__ b3,
    const float* __restrict__ m3, const float* __restrict__ v3,
    float* __restrict__ ob)
{
  int n = blockIdx.x*256 + threadIdx.x;
  if (n >= 512) return;
  float acc = fb[n];
  for (int k = 0; k < 512; ++k){
    float s = g3[k]*rsqrtf(v3[k]+EPSBN);
    float t = b3[k] - m3[k]*s;
    acc += t * fw[k*512 + n];
  }
  ob[n] = acc;
}

__global__ __launch_bounds__(256) void k_prep_smw(
    const float* __restrict__ sw, u16* __restrict__ oh, u16* __restrict__ ol)
{
  long i = (long)blockIdx.x*256 + threadIdx.x;
  if (i >= 512L*6000) return;
  int n = (int)(i % 6000); int k = (int)(i / 6000);
  long o = (long)n*512 + k;
  splitstore(sw[i], oh+o, ol+o);
}

__global__ __launch_bounds__(256) void k_sumsplit(
    const float* __restrict__ a, const float* __restrict__ b,
    u16* __restrict__ oh, u16* __restrict__ ol)
{
  int i = blockIdx.x*256 + threadIdx.x;
  if (i >= 6352*512) return;
  splitstore(a[i] + b[i], oh+i, ol+i);
}

// ---------- split-bf16 GEMM: C[M,N] = A[M,K(hi/lo)] @ Bt[N,K(hi/lo)] + bias ----------
// AMODE 0: direct A[m][k].  AMODE 1: conv gather CW=80.  AMODE 2: conv gather CW=512.
// EPI 0: f32 out. EPI 1: relu -> split out. EPI 2: clip(0,20) -> split out.
template<int AMODE, int EPI>
__global__ __launch_bounds__(256,1)
void gemm_split(const u16* __restrict__ Ah, const u16* __restrict__ Al,
                const u16* __restrict__ Bh, const u16* __restrict__ Bl,
                const float* __restrict__ bias,
                float* __restrict__ outF, u16* __restrict__ outH, u16* __restrict__ outL,
                int M, int N, int K, int Kvalid, int TIN, int TOUT)
{
  constexpr int CW = (AMODE==1) ? 80 : 512;
  const int tid  = threadIdx.x;
  const int lane = tid & 63;
  const int w    = tid >> 6;
  const int wm = w >> 1, wn = w & 1;
  const int r  = lane & 15, kg = lane >> 4;
  const int m0 = blockIdx.y * 64 + wm * 32;
  const int n0 = blockIdx.x * 64 + wn * 32;

  long abase[2];
  #pragma unroll
  for (int mt = 0; mt < 2; ++mt){
    int m = m0 + mt*16 + r;
    int mc = m < M ? m : M - 1;
    if (AMODE == 0) abase[mt] = (long)mc * K;
    else { int bb = mc / TOUT; int tt = mc - bb * TOUT; abase[mt] = ((long)bb * TIN + 2*tt) * CW; }
  }
  long bbase[2];
  #pragma unroll
  for (int nt = 0; nt < 2; ++nt){
    int n = n0 + nt*16 + r;
    int nc = n < N ? n : N - 1;
    bbase[nt] = (long)nc * K;
  }

  f32x4 acc[2][2];
  #pragma unroll
  for (int a_ = 0; a_ < 2; ++a_)
    #pragma unroll
    for (int b_ = 0; b_ < 2; ++b_) acc[a_][b_] = f32x4{0.f,0.f,0.f,0.f};

  const bf16x8 zfrag = {0,0,0,0,0,0,0,0};
  const int koff = kg * 8;
  const int KT = K >> 5;
  for (int kt = 0; kt < KT; ++kt){
    int kf = kt*32 + koff;
    bf16x8 ah[2], al[2], bh[2], bl[2];
    #pragma unroll
    for (int nt = 0; nt < 2; ++nt){
      bh[nt] = *(const bf16x8*)(Bh + bbase[nt] + kf);
      bl[nt] = *(const bf16x8*)(Bl + bbase[nt] + kf);
    }
    #pragma unroll
    for (int mt = 0; mt < 2; ++mt){
      if (AMODE == 0){
        long ao = abase[mt] + kf;
        ah[mt] = *(const bf16x8*)(Ah + ao); al[mt] = *(const bf16x8*)(Al + ao);
      } else {
        if (kf < Kvalid){
          int kw = kf / CW; int ci = kf - kw*CW;
          long ao = abase[mt] + (long)kw*CW + ci;
          ah[mt] = *(const bf16x8*)(Ah + ao); al[mt] = *(const bf16x8*)(Al + ao);
        } else { ah[mt] = zfrag; al[mt] = zfrag; }
      }
    }
    #pragma unroll
    for (int mt = 0; mt < 2; ++mt)
      #pragma unroll
      for (int nt = 0; nt < 2; ++nt){
        acc[mt][nt] = MFMA(ah[mt], bh[nt], acc[mt][nt]);
        acc[mt][nt] = MFMA(ah[mt], bl[nt], acc[mt][nt]);
        acc[mt][nt] = MFMA(al[mt], bh[nt], acc[mt][nt]);
      }
  }

  #pragma unroll
  for (int nt = 0; nt < 2; ++nt){
    int n = n0 + nt*16 + r;
    if (n >= N) continue;
    float bv = bias ? bias[n] : 0.f;
    #pragma unroll
    for (int mt = 0; mt < 2; ++mt){
      #pragma unroll
      for (int q = 0; q < 4; ++q){
        int m = m0 + mt*16 + kg*4 + q;
        if (m >= M) continue;
        float v = acc[mt][nt][q] + bv;
        if (EPI == 1) v = fmaxf(v, 0.f);
        if (EPI == 2) v = fminf(fmaxf(v, 0.f), 20.f);
        long o = (long)m * N + n;
        if (EPI == 0) outF[o] = v;
        else { u16 h = f2bf(v); outH[o] = h; outL[o] = f2bf(v - bf2f(h)); }
      }
    }
  }
}

// ---------- persistent bidirectional GRU layer ----------
// 64 blocks: dir = bx>>5, slice s = bx&31 (16 h-cols each).
// R9 protocol: epoch-fused h atoms (8B dwordx2 {payload, epoch}, fire-and-forget,
// NO producer drain, NO flags, NO release barrier — correctness proven in R8) with
// SUBSET-ONLY retry on the consumer: load once, validate per-kk slice (free VALU on
// loaded data), re-load only stale kk slices. Fixes R8's pathology (full 16KB/wave
// re-load per retry round -> +100MB FETCH, 4.1us/step). The validation loop IS the
// sync: expected ~1.5-2.5 system RTs/step vs R5's 4.5 (drain+flag+poll+load).
// Lap safety: a block overwrites buf[b] (epoch t -> t+2) only after validating ALL
// columns at epoch t+1, which implies every block finished reading buf[b] at t.
// Stale-epoch aliasing across layers/replays impossible (396/397/poison vs 1,2).
__global__ __launch_bounds__(256,1)
void gru_layer(const float* __restrict__ xp,     // [2][6352][1536]
               const u16* __restrict__ WhH, const u16* __restrict__ WhL, // [2][1536][512]
               const float* __restrict__ hbias,  // [2][1536]
               float* __restrict__ yf, float* __restrict__ yb, // [6352][512] each
               u32* __restrict__ hq_)            // [2 dirs][2 bufs][16][512][2] u32
{
  const int dir = blockIdx.x >> 5;
  const int s   = blockIdx.x & 31;
  const int tid = threadIdx.x, lane = tid & 63, w = tid >> 6;
  const int r = lane & 15, kg = lane >> 4;

  const float* xpd = xp + (long)dir * (6352L*1536);
  const u16* whh = WhH + (long)dir * (1536L*512);
  const u16* whl = WhL + (long)dir * (1536L*512);
  const float* hb = hbias + dir * 1536;
  float* y = dir ? yb : yf;
  u32* hq = hq_ + dir * 32768;

  __shared__ float red[2][4][3][64][4];   // ping-pong -> one barrier per step

  // persistent Wh fragments: wave w covers ktiles 4w..4w+3; gates g=0..2
  bf16x8 Bh[3][4], Bl[3][4];
  #pragma unroll
  for (int g = 0; g < 3; ++g){
    long nb = (long)(g*512 + s*16 + r) * 512;
    #pragma unroll
    for (int kk = 0; kk < 4; ++kk){
      int k = (w*4 + kk)*32 + kg*8;
      Bh[g][kk] = *(const bf16x8*)(whh + nb + k);
      Bl[g][kk] = *(const bf16x8*)(whl + nb + k);
    }
  }

  const int gb = tid >> 4, gj = tid & 15;
  const int gcol = s*16 + gj;
  const float bz = hb[gcol], br = hb[512 + gcol], bhh = hb[1024 + gcol];
  const int rl = ((gb >> 2) << 4) | gj;  // lane holding our (row=gb,col=gj)
  const int rq = gb & 3;
  const int cb0 = r * 512 + kg * 8;      // this lane's (row, col-group) in h image
  float hreg = 0.f;

  for (int t = 0; t < 397; ++t){
    const int tpos = dir ? (396 - t) : t;
    const long xb_ = ((long)gb*397 + tpos)*1536 + gcol;
    float xz = xpd[xb_], xr = xpd[xb_ + 512], xh = xpd[xb_ + 1024];

    f32x4 a0 = f32x4{0.f,0.f,0.f,0.f}, a1 = a0, a2 = a0;
    if (t > 0){
      const u32 tt = (u32)t;
      const u32* hqb = hq + (t & 1) * 16384;

      u32x4 q[4][4];
      u32 need = 0xFu;                    // wave-uniform kk bitmask
      while (need){
        #pragma unroll
        for (int kk = 0; kk < 4; ++kk){
          if (need & (1u << kk)){
            const u32* pk = hqb + ((cb0 + (w*4 + kk)*32) << 1);
            #pragma unroll
            for (int j = 0; j < 4; ++j) q[kk][j] = ldq_sys(pk + j*4);
          }
        }
        asm volatile("s_waitcnt vmcnt(0)" ::: "memory");
        u32 nneed = 0;
        #pragma unroll
        for (int kk = 0; kk < 4; ++kk){
          if (need & (1u << kk)){
            u32 badk = 0;
            #pragma unroll
            for (int j = 0; j < 4; ++j)
              badk |= (q[kk][j].y ^ tt) | (q[kk][j].w ^ tt);
            if (__any(badk != 0)) nneed |= (1u << kk);
          }
        }
        need = nneed;
      }
      __builtin_amdgcn_sched_barrier(0);

      // repack {(hi<<16)|lo} pairs -> hi-plane / lo-plane bf16x8 fragments
      bf16x8 ah[4], al[4];
      #pragma unroll
      for (int kk = 0; kk < 4; ++kk){
        union { bf16x8 v; u32 u[4]; } A, L;
        #pragma unroll
        for (int j = 0; j < 4; ++j){
          A.u[j] = __builtin_amdgcn_perm(q[kk][j].z, q[kk][j].x, 0x07060302u); // hi0,hi1
          L.u[j] = __builtin_amdgcn_perm(q[kk][j].z, q[kk][j].x, 0x05040100u); // lo0,lo1
        }
        ah[kk] = A.v; al[kk] = L.v;
      }
      #pragma unroll
      for (int kk = 0; kk < 4; ++kk){
        a0 = MFMA(ah[kk], Bh[0][kk], a0); a0 = MFMA(ah[kk], Bl[0][kk], a0); a0 = MFMA(al[kk], Bh[0][kk], a0);
        a1 = MFMA(ah[kk], Bh[1][kk], a1); a1 = MFMA(ah[kk], Bl[1][kk], a1); a1 = MFMA(al[kk], Bh[1][kk], a1);
        a2 = MFMA(ah[kk], Bh[2][kk], a2); a2 = MFMA(ah[kk], Bl[2][kk], a2); a2 = MFMA(al[kk], Bh[2][kk], a2);
      }
    }
    const int tb = t & 1;
    *(f32x4*)&red[tb][w][0][lane][0] = a0;
    *(f32x4*)&red[tb][w][1][lane][0] = a1;
    *(f32x4*)&red[tb][w][2][lane][0] = a2;
    __syncthreads();
    float rz = bz, rr = br, rh = bhh;
    #pragma unroll
    for (int ww = 0; ww < 4; ++ww){
      rz += red[tb][ww][0][rl][rq];
      rr += red[tb][ww][1][rl][rq];
      rh += red[tb][ww][2][rl][rq];
    }
    float z  = 1.f / (1.f + __expf(-(xz + rz)));
    float rg = 1.f / (1.f + __expf(-(xr + rr)));
    float hh = fmaxf(xh + rg * rh, 0.f);
    hreg = z * hreg + (1.f - z) * hh;

    // fire-and-forget self-validating h store (payload + epoch, one 8B transaction)
    {
      u32* o = hq + ((t+1) & 1) * 16384 + ((gb*512 + gcol) << 1);
      u16 hi = f2bf(hreg); u16 lo = f2bf(hreg - bf2f(hi));
      st64_sys(o, ((u32)hi << 16) | (u32)lo, (u32)(t + 1));
    }
    y[((long)gb*397 + tpos)*512 + gcol] = hreg;  // off critical path
  }
}

// ---------- in-place row softmax on d_out [6352][6000] ----------
__global__ __launch_bounds__(256,1) void k_softmax(float* __restrict__ out)
{
  const int tid = threadIdx.x;
  float* prow = out + (long)blockIdx.x * 6000;
  float vals[24];
  float mx = -3.0e38f;
  #pragma unroll
  for (int i = 0; i < 24; ++i){
    int idx = tid + i*256;
    vals[i] = (idx < 6000) ? prow[idx] : -3.0e38f;
    mx = fmaxf(mx, vals[i]);
  }
  #pragma unroll
  for (int o = 32; o; o >>= 1) mx = fmaxf(mx, __shfl_xor(mx, o));
  __shared__ float sred[4];
  if ((tid & 63) == 0) sred[tid >> 6] = mx;
  __syncthreads();
  mx = fmaxf(fmaxf(sred[0], sred[1]), fmaxf(sred[2], sred[3]));
  __syncthreads();
  float sum = 0.f;
  #pragma unroll
  for (int i = 0; i < 24; ++i){
    int idx = tid + i*256;
    vals[i] = (idx < 6000) ? expf(vals[i] - mx) : 0.f;
    sum += vals[i];
  }
  #pragma unroll
  for (int o = 32; o; o >>= 1) sum += __shfl_xor(sum, o);
  if ((tid & 63) == 0) sred[tid >> 6] = sum;
  __syncthreads();
  sum = sred[0] + sred[1] + sred[2] + sred[3];
  float inv = 1.f / sum;
  #pragma unroll
  for (int i = 0; i < 24; ++i){
    int idx = tid + i*256;
    if (idx < 6000) prow[idx] = vals[i] * inv;
  }
}

// ---------- host ----------
extern "C" void kernel_launch(void* const* d_in, const int* in_sizes, int n_in,
                              void* d_out, int out_size, void* d_ws, size_t ws_size,
                              hipStream_t stream)
{
  (void)in_sizes; (void)n_in; (void)out_size; (void)ws_size;
  const float* x    = (const float*)d_in[0];
  const float* bn1g = (const float*)d_in[1];
  const float* bn1b = (const float*)d_in[2];
  const float* bn1m = (const float*)d_in[3];
  const float* bn1v = (const float*)d_in[4];
  const float* cw0  = (const float*)d_in[5];
  const float* cb0  = (const float*)d_in[6];
  const float* cw1  = (const float*)d_in[7];
  const float* cb1  = (const float*)d_in[8];
  const float* bn2g = (const float*)d_in[9];
  const float* bn2b = (const float*)d_in[10];
  const float* bn2m = (const float*)d_in[11];
  const float* bn2v = (const float*)d_in[12];
  const float* gwx  = (const float*)d_in[13];
  const float* gwh  = (const float*)d_in[14];
  const float* gbia = (const float*)d_in[15];
  const float* bn3g = (const float*)d_in[16];
  const float* bn3b = (const float*)d_in[17];
  const float* bn3m = (const float*)d_in[18];
  const float* bn3v = (const float*)d_in[19];
  const float* fcw  = (const float*)d_in[20];
  const float* fcb  = (const float*)d_in[21];
  const float* smw  = (const float*)d_in[22];
  const float* smb  = (const float*)d_in[23];

  char* p = (char*)d_ws;
  auto alloc = [&](size_t bytes)->char*{
    char* q = p; p += (bytes + 255) & ~(size_t)255; return q;
  };
  const size_t NX=2048000, NC1W=512*416, NC1O=12768L*512, NC2W=512*2560,
               NC2O=6352L*512, NWX=6L*1536*512, NXP=2L*6352*1536,
               NSMW=6000L*512, NFCW=512*512;

  u16 *xbnH=(u16*)alloc(NX*2),  *xbnL=(u16*)alloc(NX*2);
  u16 *c1wH=(u16*)alloc(NC1W*2),*c1wL=(u16*)alloc(NC1W*2);
  u16 *c1oH=(u16*)alloc(NC1O*2),*c1oL=(u16*)alloc(NC1O*2);
  u16 *c2wH=(u16*)alloc(NC2W*2),*c2wL=(u16*)alloc(NC2W*2);
  u16 *c2oH=(u16*)alloc(NC2O*2),*c2oL=(u16*)alloc(NC2O*2);
  u16 *wxH=(u16*)alloc(NWX*2),  *wxL=(u16*)alloc(NWX*2);
  u16 *whH=(u16*)alloc(NWX*2),  *whL=(u16*)alloc(NWX*2);
  float *xbias=(float*)alloc(6*1536*4), *hbias=(float*)alloc(6*1536*4);
  float *xp=(float*)alloc(NXP*4);
  float *yf=(float*)alloc(NC2O*4), *yb=(float*)alloc(NC2O*4);
  u16 *ysH=(u16*)alloc(NC2O*2), *ysL=(u16*)alloc(NC2O*2);
  u16 *fcwH=(u16*)alloc(NFCW*2),*fcwL=(u16*)alloc(NFCW*2);
  float *fcb2=(float*)alloc(512*4);
  u16 *fcoH=(u16*)alloc(NC2O*2),*fcoL=(u16*)alloc(NC2O*2);
  u16 *smwH=(u16*)alloc(NSMW*2),*smwL=(u16*)alloc(NSMW*2);
  u32 *hq=(u32*)alloc(2L*2*16*512*2*4);  // epoch-fused h exchange, 256 KB
  // no flags, no memset: stale/poisoned epochs never match the fresh target
  // sequence (1..397 vs 0xAAAAAAAA / previous run's {396,397} at t<=2)

  k_bn1_split<<<8000,256,0,stream>>>(x, bn1g,bn1b,bn1m,bn1v, xbnH,xbnL);
  k_prep_c1w <<<832,256,0,stream>>>(cw0, c1wH,c1wL);
  k_prep_c2w <<<5120,256,0,stream>>>(cw1, c2wH,c2wL);
  k_prep_wx  <<<18432,256,0,stream>>>(gwx, bn2g,bn2v, wxH,wxL);
  k_prep_wh  <<<18432,256,0,stream>>>(gwh, whH,whL);
  k_prep_grub<<<36,256,0,stream>>>(gbia, gwx, bn2g,bn2b,bn2m,bn2v, xbias,hbias);
  k_prep_fcw <<<1024,256,0,stream>>>(fcw, bn3g,bn3v, fcwH,fcwL);
  k_prep_fcb <<<2,256,0,stream>>>(fcw,fcb, bn3g,bn3b,bn3m,bn3v, fcb2);
  k_prep_smw <<<12000,256,0,stream>>>(smw, smwH,smwL);

  // conv1: M=12768, N=512, K=416 (valid 400), stride2 gather from xbn [16*1600][80]
  gemm_split<1,1><<<dim3(8,200),256,0,stream>>>(xbnH,xbnL, c1wH,c1wL, cb0,
      nullptr, c1oH,c1oL, 12768,512,416, 400, 1600,798);
  // conv2: M=6352, N=512, K=2560, gather from c1o [12768][512]
  gemm_split<2,1><<<dim3(8,100),256,0,stream>>>(c1oH,c1oL, c2wH,c2wL, cb1,
      nullptr, c2oH,c2oL, 6352,512,2560, 2560, 798,397);

  const u16 *aH = c2oH, *aL = c2oL;
  for (int l = 0; l < 3; ++l){
    for (int d = 0; d < 2; ++d){
      gemm_split<0,0><<<dim3(24,100),256,0,stream>>>(aH,aL,
          wxH + (size_t)(l*2+d)*786432, wxL + (size_t)(l*2+d)*786432,
          xbias + (l*2+d)*1536,
          xp + (size_t)d*9756672, nullptr,nullptr,
          6352,1536,512, 512, 0,0);
    }
    gru_layer<<<64,256,0,stream>>>(xp,
        whH + (size_t)l*2*786432, whL + (size_t)l*2*786432,
        hbias + l*2*1536, yf,yb, hq);
    k_sumsplit<<<12704,256,0,stream>>>(yf,yb, ysH,ysL);
    aH = ysH; aL = ysL;
  }

  // fc: clip(relu(x@W+b),20) -> split
  gemm_split<0,2><<<dim3(8,100),256,0,stream>>>(ysH,ysL, fcwH,fcwL, fcb2,
      nullptr, fcoH,fcoL, 6352,512,512, 512, 0,0);
  // logits -> d_out (f32), then in-place softmax
  gemm_split<0,0><<<dim3(94,100),256,0,stream>>>(fcoH,fcoL, smwH,smwL, smb,
      (float*)d_out, nullptr,nullptr, 6352,6000,512, 512, 0,0);
  k_softmax<<<6352,256,0,stream>>>((float*)d_out);
}

// Round 10
// 6050.666 us; speedup vs baseline: 1.1665x; 1.1259x over previous
//
#include <hip/hip_runtime.h>
#include <math.h>

// ---------- types / helpers ----------
using bf16x8 = __attribute__((ext_vector_type(8))) short;
using f32x4  = __attribute__((ext_vector_type(4))) float;
using u32x4  = __attribute__((ext_vector_type(4))) unsigned int;
typedef unsigned short u16;
typedef unsigned int   u32;

#define EPSBN 1e-3f

__device__ __forceinline__ u16 f2bf(float f){
  union { float f; u32 u; } c; c.f = f;
  u32 u = c.u + 0x7fffu + ((c.u >> 16) & 1u);
  return (u16)(u >> 16);
}
__device__ __forceinline__ float bf2f(u16 b){
  union { u32 u; float f; } c; c.u = ((u32)b) << 16; return c.f;
}
__device__ __forceinline__ void splitstore(float v, u16* ph, u16* pl){
  u16 h = f2bf(v); *ph = h; *pl = f2bf(v - bf2f(h));
}
__device__ __forceinline__ f32x4 MFMA(bf16x8 a, bf16x8 b, f32x4 c){
  return __builtin_amdgcn_mfma_f32_16x16x32_bf16(a, b, c, 0, 0, 0);
}

// system-scope (cross-XCD visible) accesses: sc0 sc1 bypass L1/L2, hit coherent point.
__device__ __forceinline__ void st32_sys(u32* p, u32 v){
  asm volatile("global_store_dword %0, %1, off sc0 sc1" :: "v"(p), "v"(v) : "memory");
}
__device__ __forceinline__ u32 ld32_sys(const u32* p){
  u32 r;
  asm volatile("global_load_dword %0, %1, off sc0 sc1\n\ts_waitcnt vmcnt(0)"
               : "=v"(r) : "v"(p) : "memory");
  return r;
}

// ---------- prep kernels (BN folding, transpose, bf16 hi/lo split) ----------
__global__ __launch_bounds__(256) void k_bn1_split(
    const float* __restrict__ x, const float* __restrict__ g, const float* __restrict__ b,
    const float* __restrict__ m, const float* __restrict__ v,
    u16* __restrict__ oh, u16* __restrict__ ol)
{
  int i = blockIdx.x*256 + threadIdx.x;
  if (i >= 2048000) return;
  int ci = i % 80;
  float s = g[ci] * rsqrtf(v[ci] + EPSBN);
  float val = (x[i] - m[ci]) * s + b[ci];
  splitstore(val, oh+i, ol+i);
}

// conv1 weights -> [co][kf], kf = kw*80+ci, padded K 400->416 with zeros
__global__ __launch_bounds__(256) void k_prep_c1w(
    const float* __restrict__ w0, u16* __restrict__ oh, u16* __restrict__ ol)
{
  int i = blockIdx.x*256 + threadIdx.x;
  if (i >= 512*416) return;
  int co = i / 416, kf = i - co*416;
  float val = 0.f;
  if (kf < 400){ int kw = kf/80, ci = kf - kw*80; val = w0[(kw*80+ci)*512 + co]; }
  splitstore(val, oh+i, ol+i);
}

// conv2 weights -> [co][kf], kf = kw*512+ci  (K=2560)
__global__ __launch_bounds__(256) void k_prep_c2w(
    const float* __restrict__ w1, u16* __restrict__ oh, u16* __restrict__ ol)
{
  int i = blockIdx.x*256 + threadIdx.x;
  if (i >= 5*512*512) return;
  int co = i & 511, ci = (i >> 9) & 511, kw = i >> 18;
  long o = (long)co*2560 + kw*512 + ci;
  splitstore(w1[i], oh+o, ol+o);
}

// gru Wx -> [l*2+d][n][k], BN2 scale folded into layer-0 rows
__global__ __launch_bounds__(256) void k_prep_wx(
    const float* __restrict__ wx, const float* __restrict__ g2, const float* __restrict__ v2,
    u16* __restrict__ oh, u16* __restrict__ ol)
{
  long i = (long)blockIdx.x*256 + threadIdx.x;
  if (i >= 6L*512*1536) return;
  int n = (int)(i % 1536); long r2 = i / 1536; int k = (int)(r2 % 512); int ld = (int)(r2 / 512);
  float s = (ld < 2) ? g2[k]*rsqrtf(v2[k]+EPSBN) : 1.f;
  long o = ((long)ld*1536 + n)*512 + k;
  splitstore(wx[i]*s, oh+o, ol+o);
}

__global__ __launch_bounds__(256) void k_prep_wh(
    const float* __restrict__ wh, u16* __restrict__ oh, u16* __restrict__ ol)
{
  long i = (long)blockIdx.x*256 + threadIdx.x;
  if (i >= 6L*512*1536) return;
  int n = (int)(i % 1536); long r2 = i / 1536; int k = (int)(r2 % 512); int ld = (int)(r2 / 512);
  long o = ((long)ld*1536 + n)*512 + k;
  splitstore(wh[i], oh+o, ol+o);
}

// gru biases: xbias[ld][n] = input bias (+ t2 @ Wx for layer 0), hbias = recurrent bias
__global__ __launch_bounds__(256) void k_prep_grub(
    const float* __restrict__ gb, const float* __restrict__ wx,
    const float* __restrict__ g2, const float* __restrict__ b2,
    const float* __restrict__ m2, const float* __restrict__ v2,
    float* __restrict__ xbias, float* __restrict__ hbias)
{
  int i = blockIdx.x*256 + threadIdx.x;
  if (i >= 6*1536) return;
  int n = i % 1536, ld = i / 1536;
  float xv = gb[(ld*2 + 0)*1536 + n];
  float hv = gb[(ld*2 + 1)*1536 + n];
  if (ld < 2){
    float acc = 0.f;
    for (int k = 0; k < 512; ++k){
      float s = g2[k]*rsqrtf(v2[k]+EPSBN);
      float t = b2[k] - m2[k]*s;
      acc += t * wx[((long)ld*512 + k)*1536 + n];
    }
    xv += acc;
  }
  xbias[i] = xv; hbias[i] = hv;
}

// fc weights with BN3 fold -> [n][k]
__global__ __launch_bounds__(256) void k_prep_fcw(
    const float* __restrict__ fw, const float* __restrict__ g3, const float* __restrict__ v3,
    u16* __restrict__ oh, u16* __restrict__ ol)
{
  int i = blockIdx.x*256 + threadIdx.x;
  if (i >= 512*512) return;
  int n = i & 511, k = i >> 9;
  float s = g3[k]*rsqrtf(v3[k]+EPSBN);
  long o = (long)n*512 + k;
  splitstore(fw[i]*s, oh+o, ol+o);
}

__global__ __launch_bounds__(256) void k_prep_fcb(
    const float* __restrict__ fw, const float* __restrict__ fb,
    const float* __restrict__ g3, const float* __restrict__ b3,
    const float* __restrict__ m3, const float* __restrict__ v3,
    float* __restrict__ ob)
{
  int n = blockIdx.x*256 + threadIdx.x;
  if (n >= 512) return;
  float acc = fb[n];
  for (int k = 0; k < 512; ++k){
    float s = g3[k]*rsqrtf(v3[k]+EPSBN);
    float t = b3[k] - m3[k]*s;
    acc += t * fw[k*512 + n];
  }
  ob[n] = acc;
}

__global__ __launch_bounds__(256) void k_prep_smw(
    const float* __restrict__ sw, u16* __restrict__ oh, u16* __restrict__ ol)
{
  long i = (long)blockIdx.x*256 + threadIdx.x;
  if (i >= 512L*6000) return;
  int n = (int)(i % 6000); int k = (int)(i / 6000);
  long o = (long)n*512 + k;
  splitstore(sw[i], oh+o, ol+o);
}

__global__ __launch_bounds__(256) void k_sumsplit(
    const float* __restrict__ a, const float* __restrict__ b,
    u16* __restrict__ oh, u16* __restrict__ ol)
{
  int i = blockIdx.x*256 + threadIdx.x;
  if (i >= 6352*512) return;
  splitstore(a[i] + b[i], oh+i, ol+i);
}

// ---------- split-bf16 GEMM: C[M,N] = A[M,K(hi/lo)] @ Bt[N,K(hi/lo)] + bias ----------
// AMODE 0: direct A[m][k].  AMODE 1: conv gather CW=80.  AMODE 2: conv gather CW=512.
// EPI 0: f32 out. EPI 1: relu -> split out. EPI 2: clip(0,20) -> split out.
template<int AMODE, int EPI>
__global__ __launch_bounds__(256,1)
void gemm_split(const u16* __restrict__ Ah, const u16* __restrict__ Al,
                const u16* __restrict__ Bh, const u16* __restrict__ Bl,
                const float* __restrict__ bias,
                float* __restrict__ outF, u16* __restrict__ outH, u16* __restrict__ outL,
                int M, int N, int K, int Kvalid, int TIN, int TOUT)
{
  constexpr int CW = (AMODE==1) ? 80 : 512;
  const int tid  = threadIdx.x;
  const int lane = tid & 63;
  const int w    = tid >> 6;
  const int wm = w >> 1, wn = w & 1;
  const int r  = lane & 15, kg = lane >> 4;
  const int m0 = blockIdx.y * 64 + wm * 32;
  const int n0 = blockIdx.x * 64 + wn * 32;

  long abase[2];
  #pragma unroll
  for (int mt = 0; mt < 2; ++mt){
    int m = m0 + mt*16 + r;
    int mc = m < M ? m : M - 1;
    if (AMODE == 0) abase[mt] = (long)mc * K;
    else { int bb = mc / TOUT; int tt = mc - bb * TOUT; abase[mt] = ((long)bb * TIN + 2*tt) * CW; }
  }
  long bbase[2];
  #pragma unroll
  for (int nt = 0; nt < 2; ++nt){
    int n = n0 + nt*16 + r;
    int nc = n < N ? n : N - 1;
    bbase[nt] = (long)nc * K;
  }

  f32x4 acc[2][2];
  #pragma unroll
  for (int a_ = 0; a_ < 2; ++a_)
    #pragma unroll
    for (int b_ = 0; b_ < 2; ++b_) acc[a_][b_] = f32x4{0.f,0.f,0.f,0.f};

  const bf16x8 zfrag = {0,0,0,0,0,0,0,0};
  const int koff = kg * 8;
  const int KT = K >> 5;
  for (int kt = 0; kt < KT; ++kt){
    int kf = kt*32 + koff;
    bf16x8 ah[2], al[2], bh[2], bl[2];
    #pragma unroll
    for (int nt = 0; nt < 2; ++nt){
      bh[nt] = *(const bf16x8*)(Bh + bbase[nt] + kf);
      bl[nt] = *(const bf16x8*)(Bl + bbase[nt] + kf);
    }
    #pragma unroll
    for (int mt = 0; mt < 2; ++mt){
      if (AMODE == 0){
        long ao = abase[mt] + kf;
        ah[mt] = *(const bf16x8*)(Ah + ao); al[mt] = *(const bf16x8*)(Al + ao);
      } else {
        if (kf < Kvalid){
          int kw = kf / CW; int ci = kf - kw*CW;
          long ao = abase[mt] + (long)kw*CW + ci;
          ah[mt] = *(const bf16x8*)(Ah + ao); al[mt] = *(const bf16x8*)(Al + ao);
        } else { ah[mt] = zfrag; al[mt] = zfrag; }
      }
    }
    #pragma unroll
    for (int mt = 0; mt < 2; ++mt)
      #pragma unroll
      for (int nt = 0; nt < 2; ++nt){
        acc[mt][nt] = MFMA(ah[mt], bh[nt], acc[mt][nt]);
        acc[mt][nt] = MFMA(ah[mt], bl[nt], acc[mt][nt]);
        acc[mt][nt] = MFMA(al[mt], bh[nt], acc[mt][nt]);
      }
  }

  #pragma unroll
  for (int nt = 0; nt < 2; ++nt){
    int n = n0 + nt*16 + r;
    if (n >= N) continue;
    float bv = bias ? bias[n] : 0.f;
    #pragma unroll
    for (int mt = 0; mt < 2; ++mt){
      #pragma unroll
      for (int q = 0; q < 4; ++q){
        int m = m0 + mt*16 + kg*4 + q;
        if (m >= M) continue;
        float v = acc[mt][nt][q] + bv;
        if (EPI == 1) v = fmaxf(v, 0.f);
        if (EPI == 2) v = fminf(fmaxf(v, 0.f), 20.f);
        long o = (long)m * N + n;
        if (EPI == 0) outF[o] = v;
        else { u16 h = f2bf(v); outH[o] = h; outL[o] = f2bf(v - bf2f(h)); }
      }
    }
  }
}

// ---------- persistent bidirectional GRU layer ----------
// 64 blocks: dir = bx>>5, slice s = bx&31 (16 h-cols each).
// R10 protocol — time-indexed exchange:
//   * h(t) lives at FRESH addresses hq[t][dir][16][512] (u32 = hi<<16|lo). Producer
//     stores sc1 (to coherent point), vmcnt(0) drain, posts its flag (sc1, 64B-strided
//     slot, value (l+1)*1000+t+1, monotonic, >= compare).
//   * Consumer polls the 32 tiny flags at sys scope (cheap rounds), then pulls the
//     image with PLAIN CACHED loads: addresses are never-before-touched, so the first
//     block per XCD misses and fills its local L2 FRESH (flag seen => data is at the
//     coherent point), and the other ~7 blocks on that XCD hit L2. 8x less fabric
//     traffic than sc1 pulls; stale lines impossible by construction (no reuse).
//   * Replay/garbage safety: flags memset to 0 inside the graph each launch; hq needs
//     no reset (reads gated by this launch's flags).
__global__ __launch_bounds__(256,1)
void gru_layer(const float* __restrict__ xp,     // [2][6352][1536]
               const u16* __restrict__ WhH, const u16* __restrict__ WhL, // [2][1536][512]
               const float* __restrict__ hbias,  // [2][1536]
               float* __restrict__ yf, float* __restrict__ yb, // [6352][512] each
               u32* __restrict__ hq,             // [398][2][16][512] u32, time-indexed
               u32* __restrict__ flags,          // [2][32] slots, 64B-strided (16 u32)
               u32 lcode)                        // (layer+1)*1000
{
  const int dir = blockIdx.x >> 5;
  const int s   = blockIdx.x & 31;
  const int tid = threadIdx.x, lane = tid & 63, w = tid >> 6;
  const int r = lane & 15, kg = lane >> 4;

  const float* xpd = xp + (long)dir * (6352L*1536);
  const u16* whh = WhH + (long)dir * (1536L*512);
  const u16* whl = WhL + (long)dir * (1536L*512);
  const float* hb = hbias + dir * 1536;
  float* y = dir ? yb : yf;
  u32* flg = flags + dir * 512;          // 32 slots x 16 u32 (64 B stride)

  __shared__ float red[2][4][3][64][4];  // ping-pong -> one barrier per step

  // persistent Wh fragments: wave w covers ktiles 4w..4w+3; gates g=0..2
  bf16x8 Bh[3][4], Bl[3][4];
  #pragma unroll
  for (int g = 0; g < 3; ++g){
    long nb = (long)(g*512 + s*16 + r) * 512;
    #pragma unroll
    for (int kk = 0; kk < 4; ++kk){
      int k = (w*4 + kk)*32 + kg*8;
      Bh[g][kk] = *(const bf16x8*)(whh + nb + k);
      Bl[g][kk] = *(const bf16x8*)(whl + nb + k);
    }
  }

  const int gb = tid >> 4, gj = tid & 15;
  const int gcol = s*16 + gj;
  const float bz = hb[gcol], br = hb[512 + gcol], bhh = hb[1024 + gcol];
  const int rl = ((gb >> 2) << 4) | gj;  // lane holding our (row=gb,col=gj)
  const int rq = gb & 3;
  float hreg = 0.f;

  for (int t = 0; t < 397; ++t){
    const int tpos = dir ? (396 - t) : t;
    const long xb_ = ((long)gb*397 + tpos)*1536 + gcol;
    float xz = xpd[xb_], xr = xpd[xb_ + 512], xh = xpd[xb_ + 1024];

    f32x4 a0 = f32x4{0.f,0.f,0.f,0.f}, a1 = a0, a2 = a0;
    if (t > 0){
      // cheap sys-scope flag poll (>=, monotonic value encoding)
      if (w == 0){
        const u32 tgt = lcode + (u32)t;
        for (;;){
          int done = 1;
          if (lane < 32) done = (ld32_sys(flg + lane*16) >= tgt);
          if (__all(done)) break;
        }
      }
      __syncthreads();   // orders the cached data loads after flag confirmation

      // plain cached pull of the step-t image (fresh addresses -> L2-shared per XCD)
      const u32* hqs = hq + ((long)t*2 + dir) * 8192;
      const int cbase = r*512 + kg*8;
      u32x4 q0[4], q1[4];
      #pragma unroll
      for (int kk = 0; kk < 4; ++kk){
        const u32x4* pp = (const u32x4*)(hqs + cbase + (w*4 + kk)*32);
        q0[kk] = pp[0]; q1[kk] = pp[1];
      }

      // repack {(hi<<16)|lo} cols -> hi-plane / lo-plane bf16x8 fragments
      bf16x8 ah[4], al[4];
      #pragma unroll
      for (int kk = 0; kk < 4; ++kk){
        union { bf16x8 v; u32 u[4]; } A, L;
        A.u[0] = __builtin_amdgcn_perm(q0[kk].y, q0[kk].x, 0x07060302u);
        L.u[0] = __builtin_amdgcn_perm(q0[kk].y, q0[kk].x, 0x05040100u);
        A.u[1] = __builtin_amdgcn_perm(q0[kk].w, q0[kk].z, 0x07060302u);
        L.u[1] = __builtin_amdgcn_perm(q0[kk].w, q0[kk].z, 0x05040100u);
        A.u[2] = __builtin_amdgcn_perm(q1[kk].y, q1[kk].x, 0x07060302u);
        L.u[2] = __builtin_amdgcn_perm(q1[kk].y, q1[kk].x, 0x05040100u);
        A.u[3] = __builtin_amdgcn_perm(q1[kk].w, q1[kk].z, 0x07060302u);
        L.u[3] = __builtin_amdgcn_perm(q1[kk].w, q1[kk].z, 0x05040100u);
        ah[kk] = A.v; al[kk] = L.v;
      }
      #pragma unroll
      for (int kk = 0; kk < 4; ++kk){
        a0 = MFMA(ah[kk], Bh[0][kk], a0); a0 = MFMA(ah[kk], Bl[0][kk], a0); a0 = MFMA(al[kk], Bh[0][kk], a0);
        a1 = MFMA(ah[kk], Bh[1][kk], a1); a1 = MFMA(ah[kk], Bl[1][kk], a1); a1 = MFMA(al[kk], Bh[1][kk], a1);
        a2 = MFMA(ah[kk], Bh[2][kk], a2); a2 = MFMA(ah[kk], Bl[2][kk], a2); a2 = MFMA(al[kk], Bh[2][kk], a2);
      }
    }
    const int tb = t & 1;
    *(f32x4*)&red[tb][w][0][lane][0] = a0;
    *(f32x4*)&red[tb][w][1][lane][0] = a1;
    *(f32x4*)&red[tb][w][2][lane][0] = a2;
    __syncthreads();
    float rz = bz, rr = br, rh = bhh;
    #pragma unroll
    for (int ww = 0; ww < 4; ++ww){
      rz += red[tb][ww][0][rl][rq];
      rr += red[tb][ww][1][rl][rq];
      rh += red[tb][ww][2][rl][rq];
    }
    float z  = 1.f / (1.f + __expf(-(xz + rz)));
    float rg = 1.f / (1.f + __expf(-(xr + rr)));
    float hh = fmaxf(xh + rg * rh, 0.f);
    hreg = z * hreg + (1.f - z) * hh;

    // release: sc1 h store to FRESH step-(t+1) region -> drain -> barrier -> flag
    {
      u32* o = hq + ((long)(t+1)*2 + dir) * 8192 + gb*512 + gcol;
      u16 hi = f2bf(hreg); u16 lo = f2bf(hreg - bf2f(hi));
      st32_sys(o, ((u32)hi << 16) | (u32)lo);
    }
    asm volatile("s_waitcnt vmcnt(0)" ::: "memory");
    __syncthreads();
    if (tid == 0) st32_sys(flg + s*16, lcode + (u32)(t + 1));
    y[((long)gb*397 + tpos)*512 + gcol] = hreg;  // off critical path
  }
}

// ---------- in-place row softmax on d_out [6352][6000] ----------
__global__ __launch_bounds__(256,1) void k_softmax(float* __restrict__ out)
{
  const int tid = threadIdx.x;
  float* prow = out + (long)blockIdx.x * 6000;
  float vals[24];
  float mx = -3.0e38f;
  #pragma unroll
  for (int i = 0; i < 24; ++i){
    int idx = tid + i*256;
    vals[i] = (idx < 6000) ? prow[idx] : -3.0e38f;
    mx = fmaxf(mx, vals[i]);
  }
  #pragma unroll
  for (int o = 32; o; o >>= 1) mx = fmaxf(mx, __shfl_xor(mx, o));
  __shared__ float sred[4];
  if ((tid & 63) == 0) sred[tid >> 6] = mx;
  __syncthreads();
  mx = fmaxf(fmaxf(sred[0], sred[1]), fmaxf(sred[2], sred[3]));
  __syncthreads();
  float sum = 0.f;
  #pragma unroll
  for (int i = 0; i < 24; ++i){
    int idx = tid + i*256;
    vals[i] = (idx < 6000) ? expf(vals[i] - mx) : 0.f;
    sum += vals[i];
  }
  #pragma unroll
  for (int o = 32; o; o >>= 1) sum += __shfl_xor(sum, o);
  if ((tid & 63) == 0) sred[tid >> 6] = sum;
  __syncthreads();
  sum = sred[0] + sred[1] + sred[2] + sred[3];
  float inv = 1.f / sum;
  #pragma unroll
  for (int i = 0; i < 24; ++i){
    int idx = tid + i*256;
    if (idx < 6000) prow[idx] = vals[i] * inv;
  }
}

// ---------- host ----------
extern "C" void kernel_launch(void* const* d_in, const int* in_sizes, int n_in,
                              void* d_out, int out_size, void* d_ws, size_t ws_size,
                              hipStream_t stream)
{
  (void)in_sizes; (void)n_in; (void)out_size; (void)ws_size;
  const float* x    = (const float*)d_in[0];
  const float* bn1g = (const float*)d_in[1];
  const float* bn1b = (const float*)d_in[2];
  const float* bn1m = (const float*)d_in[3];
  const float* bn1v = (const float*)d_in[4];
  const float* cw0  = (const float*)d_in[5];
  const float* cb0  = (const float*)d_in[6];
  const float* cw1  = (const float*)d_in[7];
  const float* cb1  = (const float*)d_in[8];
  const float* bn2g = (const float*)d_in[9];
  const float* bn2b = (const float*)d_in[10];
  const float* bn2m = (const float*)d_in[11];
  const float* bn2v = (const float*)d_in[12];
  const float* gwx  = (const float*)d_in[13];
  const float* gwh  = (const float*)d_in[14];
  const float* gbia = (const float*)d_in[15];
  const float* bn3g = (const float*)d_in[16];
  const float* bn3b = (const float*)d_in[17];
  const float* bn3m = (const float*)d_in[18];
  const float* bn3v = (const float*)d_in[19];
  const float* fcw  = (const float*)d_in[20];
  const float* fcb  = (const float*)d_in[21];
  const float* smw  = (const float*)d_in[22];
  const float* smb  = (const float*)d_in[23];

  char* p = (char*)d_ws;
  auto alloc = [&](size_t bytes)->char*{
    char* q = p; p += (bytes + 255) & ~(size_t)255; return q;
  };
  const size_t NX=2048000, NC1W=512*416, NC1O=12768L*512, NC2W=512*2560,
               NC2O=6352L*512, NWX=6L*1536*512, NXP=2L*6352*1536,
               NSMW=6000L*512, NFCW=512*512;

  u16 *xbnH=(u16*)alloc(NX*2),  *xbnL=(u16*)alloc(NX*2);
  u16 *c1wH=(u16*)alloc(NC1W*2),*c1wL=(u16*)alloc(NC1W*2);
  u16 *c1oH=(u16*)alloc(NC1O*2),*c1oL=(u16*)alloc(NC1O*2);
  u16 *c2wH=(u16*)alloc(NC2W*2),*c2wL=(u16*)alloc(NC2W*2);
  u16 *c2oH=(u16*)alloc(NC2O*2),*c2oL=(u16*)alloc(NC2O*2);
  u16 *wxH=(u16*)alloc(NWX*2),  *wxL=(u16*)alloc(NWX*2);
  u16 *whH=(u16*)alloc(NWX*2),  *whL=(u16*)alloc(NWX*2);
  float *xbias=(float*)alloc(6*1536*4), *hbias=(float*)alloc(6*1536*4);
  float *xp=(float*)alloc(NXP*4);
  float *yf=(float*)alloc(NC2O*4), *yb=(float*)alloc(NC2O*4);
  u16 *ysH=(u16*)alloc(NC2O*2), *ysL=(u16*)alloc(NC2O*2);
  u16 *fcwH=(u16*)alloc(NFCW*2),*fcwL=(u16*)alloc(NFCW*2);
  float *fcb2=(float*)alloc(512*4);
  u16 *fcoH=(u16*)alloc(NC2O*2),*fcoL=(u16*)alloc(NC2O*2);
  u16 *smwH=(u16*)alloc(NSMW*2),*smwL=(u16*)alloc(NSMW*2);
  u32 *hq=(u32*)alloc(398L*2*8192*4);     // time-indexed h exchange ring, 26 MB
  u32 *flags=(u32*)alloc(2*512*4);        // [dir][32 slots x 16 u32], 4 KB

  hipMemsetAsync(flags, 0, 2*512*4, stream);   // in-graph: resets every replay

  k_bn1_split<<<8000,256,0,stream>>>(x, bn1g,bn1b,bn1m,bn1v, xbnH,xbnL);
  k_prep_c1w <<<832,256,0,stream>>>(cw0, c1wH,c1wL);
  k_prep_c2w <<<5120,256,0,stream>>>(cw1, c2wH,c2wL);
  k_prep_wx  <<<18432,256,0,stream>>>(gwx, bn2g,bn2v, wxH,wxL);
  k_prep_wh  <<<18432,256,0,stream>>>(gwh, whH,whL);
  k_prep_grub<<<36,256,0,stream>>>(gbia, gwx, bn2g,bn2b,bn2m,bn2v, xbias,hbias);
  k_prep_fcw <<<1024,256,0,stream>>>(fcw, bn3g,bn3v, fcwH,fcwL);
  k_prep_fcb <<<2,256,0,stream>>>(fcw,fcb, bn3g,bn3b,bn3m,bn3v, fcb2);
  k_prep_smw <<<12000,256,0,stream>>>(smw, smwH,smwL);

  // conv1: M=12768, N=512, K=416 (valid 400), stride2 gather from xbn [16*1600][80]
  gemm_split<1,1><<<dim3(8,200),256,0,stream>>>(xbnH,xbnL, c1wH,c1wL, cb0,
      nullptr, c1oH,c1oL, 12768,512,416, 400, 1600,798);
  // conv2: M=6352, N=512, K=2560, gather from c1o [12768][512]
  gemm_split<2,1><<<dim3(8,100),256,0,stream>>>(c1oH,c1oL, c2wH,c2wL, cb1,
      nullptr, c2oH,c2oL, 6352,512,2560, 2560, 798,397);

  const u16 *aH = c2oH, *aL = c2oL;
  for (int l = 0; l < 3; ++l){
    for (int d = 0; d < 2; ++d){
      gemm_split<0,0><<<dim3(24,100),256,0,stream>>>(aH,aL,
          wxH + (size_t)(l*2+d)*786432, wxL + (size_t)(l*2+d)*786432,
          xbias + (l*2+d)*1536,
          xp + (size_t)d*9756672, nullptr,nullptr,
          6352,1536,512, 512, 0,0);
    }
    gru_layer<<<64,256,0,stream>>>(xp,
        whH + (size_t)l*2*786432, whL + (size_t)l*2*786432,
        hbias + l*2*1536, yf,yb, hq, flags, (u32)((l+1)*1000));
    k_sumsplit<<<12704,256,0,stream>>>(yf,yb, ysH,ysL);
    aH = ysH; aL = ysL;
  }

  // fc: clip(relu(x@W+b),20) -> split
  gemm_split<0,2><<<dim3(8,100),256,0,stream>>>(ysH,ysL, fcwH,fcwL, fcb2,
      nullptr, fcoH,fcoL, 6352,512,512, 512, 0,0);
  // logits -> d_out (f32), then in-place softmax
  gemm_split<0,0><<<dim3(94,100),256,0,stream>>>(fcoH,fcoL, smwH,smwL, smb,
      (float*)d_out, nullptr,nullptr, 6352,6000,512, 512, 0,0);
  k_softmax<<<6352,256,0,stream>>>((float*)d_out);
}

// Round 11
// 6017.642 us; speedup vs baseline: 1.1729x; 1.0055x over previous
//
#include <hip/hip_runtime.h>
#include <math.h>

// ---------- types / helpers ----------
using bf16x8 = __attribute__((ext_vector_type(8))) short;
using f32x4  = __attribute__((ext_vector_type(4))) float;
using u32x4  = __attribute__((ext_vector_type(4))) unsigned int;
typedef unsigned short u16;
typedef unsigned int   u32;

#define EPSBN 1e-3f

__device__ __forceinline__ u16 f2bf(float f){
  union { float f; u32 u; } c; c.f = f;
  u32 u = c.u + 0x7fffu + ((c.u >> 16) & 1u);
  return (u16)(u >> 16);
}
__device__ __forceinline__ float bf2f(u16 b){
  union { u32 u; float f; } c; c.u = ((u32)b) << 16; return c.f;
}
__device__ __forceinline__ void splitstore(float v, u16* ph, u16* pl){
  u16 h = f2bf(v); *ph = h; *pl = f2bf(v - bf2f(h));
}
__device__ __forceinline__ f32x4 MFMA(bf16x8 a, bf16x8 b, f32x4 c){
  return __builtin_amdgcn_mfma_f32_16x16x32_bf16(a, b, c, 0, 0, 0);
}

// system-scope (cross-XCD visible) accesses: sc0 sc1 bypass L1/L2, hit coherent point.
__device__ __forceinline__ void st32_sys(u32* p, u32 v){
  asm volatile("global_store_dword %0, %1, off sc0 sc1" :: "v"(p), "v"(v) : "memory");
}
__device__ __forceinline__ u32 ld32_sys(const u32* p){
  u32 r;
  asm volatile("global_load_dword %0, %1, off sc0 sc1\n\ts_waitcnt vmcnt(0)"
               : "=v"(r) : "v"(p) : "memory");
  return r;
}

// ---------- prep kernels (BN folding, transpose, bf16 hi/lo split) ----------
__global__ __launch_bounds__(256) void k_bn1_split(
    const float* __restrict__ x, const float* __restrict__ g, const float* __restrict__ b,
    const float* __restrict__ m, const float* __restrict__ v,
    u16* __restrict__ oh, u16* __restrict__ ol)
{
  int i = blockIdx.x*256 + threadIdx.x;
  if (i >= 2048000) return;
  int ci = i % 80;
  float s = g[ci] * rsqrtf(v[ci] + EPSBN);
  float val = (x[i] - m[ci]) * s + b[ci];
  splitstore(val, oh+i, ol+i);
}

// conv1 weights -> [co][kf], kf = kw*80+ci, padded K 400->416 with zeros
__global__ __launch_bounds__(256) void k_prep_c1w(
    const float* __restrict__ w0, u16* __restrict__ oh, u16* __restrict__ ol)
{
  int i = blockIdx.x*256 + threadIdx.x;
  if (i >= 512*416) return;
  int co = i / 416, kf = i - co*416;
  float val = 0.f;
  if (kf < 400){ int kw = kf/80, ci = kf - kw*80; val = w0[(kw*80+ci)*512 + co]; }
  splitstore(val, oh+i, ol+i);
}

// conv2 weights -> [co][kf], kf = kw*512+ci  (K=2560)
__global__ __launch_bounds__(256) void k_prep_c2w(
    const float* __restrict__ w1, u16* __restrict__ oh, u16* __restrict__ ol)
{
  int i = blockIdx.x*256 + threadIdx.x;
  if (i >= 5*512*512) return;
  int co = i & 511, ci = (i >> 9) & 511, kw = i >> 18;
  long o = (long)co*2560 + kw*512 + ci;
  splitstore(w1[i], oh+o, ol+o);
}

// gru Wx -> [l*2+d][n][k], BN2 scale folded into layer-0 rows
__global__ __launch_bounds__(256) void k_prep_wx(
    const float* __restrict__ wx, const float* __restrict__ g2, const float* __restrict__ v2,
    u16* __restrict__ oh, u16* __restrict__ ol)
{
  long i = (long)blockIdx.x*256 + threadIdx.x;
  if (i >= 6L*512*1536) return;
  int n = (int)(i % 1536); long r2 = i / 1536; int k = (int)(r2 % 512); int ld = (int)(r2 / 512);
  float s = (ld < 2) ? g2[k]*rsqrtf(v2[k]+EPSBN) : 1.f;
  long o = ((long)ld*1536 + n)*512 + k;
  splitstore(wx[i]*s, oh+o, ol+o);
}

__global__ __launch_bounds__(256) void k_prep_wh(
    const float* __restrict__ wh, u16* __restrict__ oh, u16* __restrict__ ol)
{
  long i = (long)blockIdx.x*256 + threadIdx.x;
  if (i >= 6L*512*1536) return;
  int n = (int)(i % 1536); long r2 = i / 1536; int k = (int)(r2 % 512); int ld = (int)(r2 / 512);
  long o = ((long)ld*1536 + n)*512 + k;
  splitstore(wh[i], oh+o, ol+o);
}

// gru biases: xbias[ld][n] = input bias (+ t2 @ Wx for layer 0), hbias = recurrent bias
__global__ __launch_bounds__(256) void k_prep_grub(
    const float* __restrict__ gb, const float* __restrict__ wx,
    const float* __restrict__ g2, const float* __restrict__ b2,
    const float* __restrict__ m2, const float* __restrict__ v2,
    float* __restrict__ xbias, float* __restrict__ hbias)
{
  int i = blockIdx.x*256 + threadIdx.x;
  if (i >= 6*1536) return;
  int n = i % 1536, ld = i / 1536;
  float xv = gb[(ld*2 + 0)*1536 + n];
  float hv = gb[(ld*2 + 1)*1536 + n];
  if (ld < 2){
    float acc = 0.f;
    for (int k = 0; k < 512; ++k){
      float s = g2[k]*rsqrtf(v2[k]+EPSBN);
      float t = b2[k] - m2[k]*s;
      acc += t * wx[((long)ld*512 + k)*1536 + n];
    }
    xv += acc;
  }
  xbias[i] = xv; hbias[i] = hv;
}

// fc weights with BN3 fold -> [n][k]
__global__ __launch_bounds__(256) void k_prep_fcw(
    const float* __restrict__ fw, const float* __restrict__ g3, const float* __restrict__ v3,
    u16* __restrict__ oh, u16* __restrict__ ol)
{
  int i = blockIdx.x*256 + threadIdx.x;
  if (i >= 512*512) return;
  int n = i & 511, k = i >> 9;
  float s = g3[k]*rsqrtf(v3[k]+EPSBN);
  long o = (long)n*512 + k;
  splitstore(fw[i]*s, oh+o, ol+o);
}

__global__ __launch_bounds__(256) void k_prep_fcb(
    const float* __restrict__ fw, const float* __restrict__ fb,
    const float* __restrict__ g3, const float* __restrict__ b3,
    const float* __restrict__ m3, const float* __restrict__ v3,
    float* __restrict__ ob)
{
  int n = blockIdx.x*256 + threadIdx.x;
  if (n >= 512) return;
  float acc = fb[n];
  for (int k = 0; k < 512; ++k){
    float s = g3[k]*rsqrtf(v3[k]+EPSBN);
    float t = b3[k] - m3[k]*s;
    acc += t * fw[k*512 + n];
  }
  ob[n] = acc;
}

__global__ __launch_bounds__(256) void k_prep_smw(
    const float* __restrict__ sw, u16* __restrict__ oh, u16* __restrict__ ol)
{
  long i = (long)blockIdx.x*256 + threadIdx.x;
  if (i >= 512L*6000) return;
  int n = (int)(i % 6000); int k = (int)(i / 6000);
  long o = (long)n*512 + k;
  splitstore(sw[i], oh+o, ol+o);
}

__global__ __launch_bounds__(256) void k_sumsplit(
    const float* __restrict__ a, const float* __restrict__ b,
    u16* __restrict__ oh, u16* __restrict__ ol)
{
  int i = blockIdx.x*256 + threadIdx.x;
  if (i >= 6352*512) return;
  splitstore(a[i] + b[i], oh+i, ol+i);
}

// ---------- split-bf16 GEMM: C[M,N] = A[M,K(hi/lo)] @ Bt[N,K(hi/lo)] + bias ----------
// AMODE 0: direct A[m][k].  AMODE 1: conv gather CW=80.  AMODE 2: conv gather CW=512.
// EPI 0: f32 out. EPI 1: relu -> split out. EPI 2: clip(0,20) -> split out.
// R11: 1D grid + XCD-chunked swizzle (T1). nwg MUST be divisible by 8. Each XCD gets a
// contiguous wg-slab decomposed x-major (x=wg/NYB, y=wg%NYB): its B column-slice stays
// L2-resident across all y, and concurrent blocks in a slab share one A row-panel.
// Fixes the logits GEMM's 719 MB FETCH (29x over-fetch from cross-XCD B re-streaming).
template<int AMODE, int EPI>
__global__ __launch_bounds__(256,1)
void gemm_split(const u16* __restrict__ Ah, const u16* __restrict__ Al,
                const u16* __restrict__ Bh, const u16* __restrict__ Bl,
                const float* __restrict__ bias,
                float* __restrict__ outF, u16* __restrict__ outH, u16* __restrict__ outL,
                int M, int N, int K, int Kvalid, int TIN, int TOUT, int NYB)
{
  constexpr int CW = (AMODE==1) ? 80 : 512;
  const int tid  = threadIdx.x;
  const int lane = tid & 63;
  const int w    = tid >> 6;
  const int wm = w >> 1, wn = w & 1;
  const int r  = lane & 15, kg = lane >> 4;

  const int nwg = gridDim.x;
  const int q   = nwg >> 3;                       // nwg % 8 == 0 at every call site
  const int bid = blockIdx.x;
  const int wg  = (bid & 7) * q + (bid >> 3);     // XCD-chunked bijective remap
  const int bx  = wg / NYB, by = wg - bx * NYB;   // x-major: slab = contiguous x-range

  const int m0 = by * 64 + wm * 32;
  const int n0 = bx * 64 + wn * 32;

  long abase[2];
  #pragma unroll
  for (int mt = 0; mt < 2; ++mt){
    int m = m0 + mt*16 + r;
    int mc = m < M ? m : M - 1;
    if (AMODE == 0) abase[mt] = (long)mc * K;
    else { int bb = mc / TOUT; int tt = mc - bb * TOUT; abase[mt] = ((long)bb * TIN + 2*tt) * CW; }
  }
  long bbase[2];
  #pragma unroll
  for (int nt = 0; nt < 2; ++nt){
    int n = n0 + nt*16 + r;
    int nc = n < N ? n : N - 1;
    bbase[nt] = (long)nc * K;
  }

  f32x4 acc[2][2];
  #pragma unroll
  for (int a_ = 0; a_ < 2; ++a_)
    #pragma unroll
    for (int b_ = 0; b_ < 2; ++b_) acc[a_][b_] = f32x4{0.f,0.f,0.f,0.f};

  const bf16x8 zfrag = {0,0,0,0,0,0,0,0};
  const int koff = kg * 8;
  const int KT = K >> 5;
  for (int kt = 0; kt < KT; ++kt){
    int kf = kt*32 + koff;
    bf16x8 ah[2], al[2], bh[2], bl[2];
    #pragma unroll
    for (int nt = 0; nt < 2; ++nt){
      bh[nt] = *(const bf16x8*)(Bh + bbase[nt] + kf);
      bl[nt] = *(const bf16x8*)(Bl + bbase[nt] + kf);
    }
    #pragma unroll
    for (int mt = 0; mt < 2; ++mt){
      if (AMODE == 0){
        long ao = abase[mt] + kf;
        ah[mt] = *(const bf16x8*)(Ah + ao); al[mt] = *(const bf16x8*)(Al + ao);
      } else {
        if (kf < Kvalid){
          int kw = kf / CW; int ci = kf - kw*CW;
          long ao = abase[mt] + (long)kw*CW + ci;
          ah[mt] = *(const bf16x8*)(Ah + ao); al[mt] = *(const bf16x8*)(Al + ao);
        } else { ah[mt] = zfrag; al[mt] = zfrag; }
      }
    }
    #pragma unroll
    for (int mt = 0; mt < 2; ++mt)
      #pragma unroll
      for (int nt = 0; nt < 2; ++nt){
        acc[mt][nt] = MFMA(ah[mt], bh[nt], acc[mt][nt]);
        acc[mt][nt] = MFMA(ah[mt], bl[nt], acc[mt][nt]);
        acc[mt][nt] = MFMA(al[mt], bh[nt], acc[mt][nt]);
      }
  }

  #pragma unroll
  for (int nt = 0; nt < 2; ++nt){
    int n = n0 + nt*16 + r;
    if (n >= N) continue;
    float bv = bias ? bias[n] : 0.f;
    #pragma unroll
    for (int mt = 0; mt < 2; ++mt){
      #pragma unroll
      for (int q2 = 0; q2 < 4; ++q2){
        int m = m0 + mt*16 + kg*4 + q2;
        if (m >= M) continue;
        float v = acc[mt][nt][q2] + bv;
        if (EPI == 1) v = fmaxf(v, 0.f);
        if (EPI == 2) v = fminf(fmaxf(v, 0.f), 20.f);
        long o = (long)m * N + n;
        if (EPI == 0) outF[o] = v;
        else { u16 h = f2bf(v); outH[o] = h; outL[o] = f2bf(v - bf2f(h)); }
      }
    }
  }
}

// ---------- persistent bidirectional GRU layer ----------
// 64 blocks: dir = bx>>5, slice s = bx&31 (16 h-cols each).
// R10 protocol (at its measured floor ~3.2us/step across 3 protocol variants):
// time-indexed exchange — h(t) at FRESH addresses hq[t][dir][16][512] (u32=hi<<16|lo);
// producer stores sc1, vmcnt(0) drain, posts monotonic flag ((l+1)*1000+t+1, >= cmp);
// consumer polls 32 tiny flags at sys scope, then pulls the image with PLAIN CACHED
// loads (fresh addresses -> first block per XCD fills local L2, rest hit; stale lines
// impossible by construction). Flags memset in-graph each launch.
__global__ __launch_bounds__(256,1)
void gru_layer(const float* __restrict__ xp,     // [2][6352][1536]
               const u16* __restrict__ WhH, const u16* __restrict__ WhL, // [2][1536][512]
               const float* __restrict__ hbias,  // [2][1536]
               float* __restrict__ yf, float* __restrict__ yb, // [6352][512] each
               u32* __restrict__ hq,             // [398][2][16][512] u32, time-indexed
               u32* __restrict__ flags,          // [2][32] slots, 64B-strided (16 u32)
               u32 lcode)                        // (layer+1)*1000
{
  const int dir = blockIdx.x >> 5;
  const int s   = blockIdx.x & 31;
  const int tid = threadIdx.x, lane = tid & 63, w = tid >> 6;
  const int r = lane & 15, kg = lane >> 4;

  const float* xpd = xp + (long)dir * (6352L*1536);
  const u16* whh = WhH + (long)dir * (1536L*512);
  const u16* whl = WhL + (long)dir * (1536L*512);
  const float* hb = hbias + dir * 1536;
  float* y = dir ? yb : yf;
  u32* flg = flags + dir * 512;          // 32 slots x 16 u32 (64 B stride)

  __shared__ float red[2][4][3][64][4];  // ping-pong -> one barrier per step

  // persistent Wh fragments: wave w covers ktiles 4w..4w+3; gates g=0..2
  bf16x8 Bh[3][4], Bl[3][4];
  #pragma unroll
  for (int g = 0; g < 3; ++g){
    long nb = (long)(g*512 + s*16 + r) * 512;
    #pragma unroll
    for (int kk = 0; kk < 4; ++kk){
      int k = (w*4 + kk)*32 + kg*8;
      Bh[g][kk] = *(const bf16x8*)(whh + nb + k);
      Bl[g][kk] = *(const bf16x8*)(whl + nb + k);
    }
  }

  const int gb = tid >> 4, gj = tid & 15;
  const int gcol = s*16 + gj;
  const float bz = hb[gcol], br = hb[512 + gcol], bhh = hb[1024 + gcol];
  const int rl = ((gb >> 2) << 4) | gj;  // lane holding our (row=gb,col=gj)
  const int rq = gb & 3;
  float hreg = 0.f;

  for (int t = 0; t < 397; ++t){
    const int tpos = dir ? (396 - t) : t;
    const long xb_ = ((long)gb*397 + tpos)*1536 + gcol;
    float xz = xpd[xb_], xr = xpd[xb_ + 512], xh = xpd[xb_ + 1024];

    f32x4 a0 = f32x4{0.f,0.f,0.f,0.f}, a1 = a0, a2 = a0;
    if (t > 0){
      // cheap sys-scope flag poll (>=, monotonic value encoding)
      if (w == 0){
        const u32 tgt = lcode + (u32)t;
        for (;;){
          int done = 1;
          if (lane < 32) done = (ld32_sys(flg + lane*16) >= tgt);
          if (__all(done)) break;
        }
      }
      __syncthreads();   // orders the cached data loads after flag confirmation

      // plain cached pull of the step-t image (fresh addresses -> L2-shared per XCD)
      const u32* hqs = hq + ((long)t*2 + dir) * 8192;
      const int cbase = r*512 + kg*8;
      u32x4 q0[4], q1[4];
      #pragma unroll
      for (int kk = 0; kk < 4; ++kk){
        const u32x4* pp = (const u32x4*)(hqs + cbase + (w*4 + kk)*32);
        q0[kk] = pp[0]; q1[kk] = pp[1];
      }

      // repack {(hi<<16)|lo} cols -> hi-plane / lo-plane bf16x8 fragments
      bf16x8 ah[4], al[4];
      #pragma unroll
      for (int kk = 0; kk < 4; ++kk){
        union { bf16x8 v; u32 u[4]; } A, L;
        A.u[0] = __builtin_amdgcn_perm(q0[kk].y, q0[kk].x, 0x07060302u);
        L.u[0] = __builtin_amdgcn_perm(q0[kk].y, q0[kk].x, 0x05040100u);
        A.u[1] = __builtin_amdgcn_perm(q0[kk].w, q0[kk].z, 0x07060302u);
        L.u[1] = __builtin_amdgcn_perm(q0[kk].w, q0[kk].z, 0x05040100u);
        A.u[2] = __builtin_amdgcn_perm(q1[kk].y, q1[kk].x, 0x07060302u);
        L.u[2] = __builtin_amdgcn_perm(q1[kk].y, q1[kk].x, 0x05040100u);
        A.u[3] = __builtin_amdgcn_perm(q1[kk].w, q1[kk].z, 0x07060302u);
        L.u[3] = __builtin_amdgcn_perm(q1[kk].w, q1[kk].z, 0x05040100u);
        ah[kk] = A.v; al[kk] = L.v;
      }
      #pragma unroll
      for (int kk = 0; kk < 4; ++kk){
        a0 = MFMA(ah[kk], Bh[0][kk], a0); a0 = MFMA(ah[kk], Bl[0][kk], a0); a0 = MFMA(al[kk], Bh[0][kk], a0);
        a1 = MFMA(ah[kk], Bh[1][kk], a1); a1 = MFMA(ah[kk], Bl[1][kk], a1); a1 = MFMA(al[kk], Bh[1][kk], a1);
        a2 = MFMA(ah[kk], Bh[2][kk], a2); a2 = MFMA(ah[kk], Bl[2][kk], a2); a2 = MFMA(al[kk], Bh[2][kk], a2);
      }
    }
    const int tb = t & 1;
    *(f32x4*)&red[tb][w][0][lane][0] = a0;
    *(f32x4*)&red[tb][w][1][lane][0] = a1;
    *(f32x4*)&red[tb][w][2][lane][0] = a2;
    __syncthreads();
    float rz = bz, rr = br, rh = bhh;
    #pragma unroll
    for (int ww = 0; ww < 4; ++ww){
      rz += red[tb][ww][0][rl][rq];
      rr += red[tb][ww][1][rl][rq];
      rh += red[tb][ww][2][rl][rq];
    }
    float z  = 1.f / (1.f + __expf(-(xz + rz)));
    float rg = 1.f / (1.f + __expf(-(xr + rr)));
    float hh = fmaxf(xh + rg * rh, 0.f);
    hreg = z * hreg + (1.f - z) * hh;

    // release: sc1 h store to FRESH step-(t+1) region -> drain -> barrier -> flag
    {
      u32* o = hq + ((long)(t+1)*2 + dir) * 8192 + gb*512 + gcol;
      u16 hi = f2bf(hreg); u16 lo = f2bf(hreg - bf2f(hi));
      st32_sys(o, ((u32)hi << 16) | (u32)lo);
    }
    asm volatile("s_waitcnt vmcnt(0)" ::: "memory");
    __syncthreads();
    if (tid == 0) st32_sys(flg + s*16, lcode + (u32)(t + 1));
    y[((long)gb*397 + tpos)*512 + gcol] = hreg;  // off critical path
  }
}

// ---------- in-place row softmax on d_out [6352][6000] ----------
__global__ __launch_bounds__(256,1) void k_softmax(float* __restrict__ out)
{
  const int tid = threadIdx.x;
  float* prow = out + (long)blockIdx.x * 6000;
  float vals[24];
  float mx = -3.0e38f;
  #pragma unroll
  for (int i = 0; i < 24; ++i){
    int idx = tid + i*256;
    vals[i] = (idx < 6000) ? prow[idx] : -3.0e38f;
    mx = fmaxf(mx, vals[i]);
  }
  #pragma unroll
  for (int o = 32; o; o >>= 1) mx = fmaxf(mx, __shfl_xor(mx, o));
  __shared__ float sred[4];
  if ((tid & 63) == 0) sred[tid >> 6] = mx;
  __syncthreads();
  mx = fmaxf(fmaxf(sred[0], sred[1]), fmaxf(sred[2], sred[3]));
  __syncthreads();
  float sum = 0.f;
  #pragma unroll
  for (int i = 0; i < 24; ++i){
    int idx = tid + i*256;
    vals[i] = (idx < 6000) ? expf(vals[i] - mx) : 0.f;
    sum += vals[i];
  }
  #pragma unroll
  for (int o = 32; o; o >>= 1) sum += __shfl_xor(sum, o);
  if ((tid & 63) == 0) sred[tid >> 6] = sum;
  __syncthreads();
  sum = sred[0] + sred[1] + sred[2] + sred[3];
  float inv = 1.f / sum;
  #pragma unroll
  for (int i = 0; i < 24; ++i){
    int idx = tid + i*256;
    if (idx < 6000) prow[idx] = vals[i] * inv;
  }
}

// ---------- host ----------
extern "C" void kernel_launch(void* const* d_in, const int* in_sizes, int n_in,
                              void* d_out, int out_size, void* d_ws, size_t ws_size,
                              hipStream_t stream)
{
  (void)in_sizes; (void)n_in; (void)out_size; (void)ws_size;
  const float* x    = (const float*)d_in[0];
  const float* bn1g = (const float*)d_in[1];
  const float* bn1b = (const float*)d_in[2];
  const float* bn1m = (const float*)d_in[3];
  const float* bn1v = (const float*)d_in[4];
  const float* cw0  = (const float*)d_in[5];
  const float* cb0  = (const float*)d_in[6];
  const float* cw1  = (const float*)d_in[7];
  const float* cb1  = (const float*)d_in[8];
  const float* bn2g = (const float*)d_in[9];
  const float* bn2b = (const float*)d_in[10];
  const float* bn2m = (const float*)d_in[11];
  const float* bn2v = (const float*)d_in[12];
  const float* gwx  = (const float*)d_in[13];
  const float* gwh  = (const float*)d_in[14];
  const float* gbia = (const float*)d_in[15];
  const float* bn3g = (const float*)d_in[16];
  const float* bn3b = (const float*)d_in[17];
  const float* bn3m = (const float*)d_in[18];
  const float* bn3v = (const float*)d_in[19];
  const float* fcw  = (const float*)d_in[20];
  const float* fcb  = (const float*)d_in[21];
  const float* smw  = (const float*)d_in[22];
  const float* smb  = (const float*)d_in[23];

  char* p = (char*)d_ws;
  auto alloc = [&](size_t bytes)->char*{
    char* q = p; p += (bytes + 255) & ~(size_t)255; return q;
  };
  const size_t NX=2048000, NC1W=512*416, NC1O=12768L*512, NC2W=512*2560,
               NC2O=6352L*512, NWX=6L*1536*512, NXP=2L*6352*1536,
               NSMW=6000L*512, NFCW=512*512;

  u16 *xbnH=(u16*)alloc(NX*2),  *xbnL=(u16*)alloc(NX*2);
  u16 *c1wH=(u16*)alloc(NC1W*2),*c1wL=(u16*)alloc(NC1W*2);
  u16 *c1oH=(u16*)alloc(NC1O*2),*c1oL=(u16*)alloc(NC1O*2);
  u16 *c2wH=(u16*)alloc(NC2W*2),*c2wL=(u16*)alloc(NC2W*2);
  u16 *c2oH=(u16*)alloc(NC2O*2),*c2oL=(u16*)alloc(NC2O*2);
  u16 *wxH=(u16*)alloc(NWX*2),  *wxL=(u16*)alloc(NWX*2);
  u16 *whH=(u16*)alloc(NWX*2),  *whL=(u16*)alloc(NWX*2);
  float *xbias=(float*)alloc(6*1536*4), *hbias=(float*)alloc(6*1536*4);
  float *xp=(float*)alloc(NXP*4);
  float *yf=(float*)alloc(NC2O*4), *yb=(float*)alloc(NC2O*4);
  u16 *ysH=(u16*)alloc(NC2O*2), *ysL=(u16*)alloc(NC2O*2);
  u16 *fcwH=(u16*)alloc(NFCW*2),*fcwL=(u16*)alloc(NFCW*2);
  float *fcb2=(float*)alloc(512*4);
  u16 *fcoH=(u16*)alloc(NC2O*2),*fcoL=(u16*)alloc(NC2O*2);
  u16 *smwH=(u16*)alloc(NSMW*2),*smwL=(u16*)alloc(NSMW*2);
  u32 *hq=(u32*)alloc(398L*2*8192*4);     // time-indexed h exchange ring, 26 MB
  u32 *flags=(u32*)alloc(2*512*4);        // [dir][32 slots x 16 u32], 4 KB

  hipMemsetAsync(flags, 0, 2*512*4, stream);   // in-graph: resets every replay

  k_bn1_split<<<8000,256,0,stream>>>(x, bn1g,bn1b,bn1m,bn1v, xbnH,xbnL);
  k_prep_c1w <<<832,256,0,stream>>>(cw0, c1wH,c1wL);
  k_prep_c2w <<<5120,256,0,stream>>>(cw1, c2wH,c2wL);
  k_prep_wx  <<<18432,256,0,stream>>>(gwx, bn2g,bn2v, wxH,wxL);
  k_prep_wh  <<<18432,256,0,stream>>>(gwh, whH,whL);
  k_prep_grub<<<36,256,0,stream>>>(gbia, gwx, bn2g,bn2b,bn2m,bn2v, xbias,hbias);
  k_prep_fcw <<<1024,256,0,stream>>>(fcw, bn3g,bn3v, fcwH,fcwL);
  k_prep_fcb <<<2,256,0,stream>>>(fcw,fcb, bn3g,bn3b,bn3m,bn3v, fcb2);
  k_prep_smw <<<12000,256,0,stream>>>(smw, smwH,smwL);

  // conv1: M=12768, N=512, K=416 (valid 400); grid 8x200 -> 1600 (div by 8)
  gemm_split<1,1><<<1600,256,0,stream>>>(xbnH,xbnL, c1wH,c1wL, cb0,
      nullptr, c1oH,c1oL, 12768,512,416, 400, 1600,798, 200);
  // conv2: M=6352, N=512, K=2560; grid 8x100 -> 800
  gemm_split<2,1><<<800,256,0,stream>>>(c1oH,c1oL, c2wH,c2wL, cb1,
      nullptr, c2oH,c2oL, 6352,512,2560, 2560, 798,397, 100);

  const u16 *aH = c2oH, *aL = c2oL;
  for (int l = 0; l < 3; ++l){
    for (int d = 0; d < 2; ++d){
      // xp: M=6352, N=1536, K=512; grid 24x100 -> 2400
      gemm_split<0,0><<<2400,256,0,stream>>>(aH,aL,
          wxH + (size_t)(l*2+d)*786432, wxL + (size_t)(l*2+d)*786432,
          xbias + (l*2+d)*1536,
          xp + (size_t)d*9756672, nullptr,nullptr,
          6352,1536,512, 512, 0,0, 100);
    }
    gru_layer<<<64,256,0,stream>>>(xp,
        whH + (size_t)l*2*786432, whL + (size_t)l*2*786432,
        hbias + l*2*1536, yf,yb, hq, flags, (u32)((l+1)*1000));
    k_sumsplit<<<12704,256,0,stream>>>(yf,yb, ysH,ysL);
    aH = ysH; aL = ysL;
  }

  // fc: M=6352, N=512, K=512; grid 8x100 -> 800
  gemm_split<0,2><<<800,256,0,stream>>>(ysH,ysL, fcwH,fcwL, fcb2,
      nullptr, fcoH,fcoL, 6352,512,512, 512, 0,0, 100);
  // logits: M=6352, N=6000, K=512; grid 94x100 -> 9400 (div by 8: 9400/8=1175)
  gemm_split<0,0><<<9400,256,0,stream>>>(fcoH,fcoL, smwH,smwL, smb,
      (float*)d_out, nullptr,nullptr, 6352,6000,512, 512, 0,0, 100);
  k_softmax<<<6352,256,0,stream>>>((float*)d_out);
}

// Round 12
// 4971.059 us; speedup vs baseline: 1.4199x; 1.2105x over previous
//
#include <hip/hip_runtime.h>
#include <math.h>

// ---------- types / helpers ----------
using bf16x8 = __attribute__((ext_vector_type(8))) short;
using f32x4  = __attribute__((ext_vector_type(4))) float;
using u32x4  = __attribute__((ext_vector_type(4))) unsigned int;
typedef unsigned short u16;
typedef unsigned int   u32;

#define EPSBN 1e-3f

__device__ __forceinline__ u16 f2bf(float f){
  union { float f; u32 u; } c; c.f = f;
  u32 u = c.u + 0x7fffu + ((c.u >> 16) & 1u);
  return (u16)(u >> 16);
}
__device__ __forceinline__ float bf2f(u16 b){
  union { u32 u; float f; } c; c.u = ((u32)b) << 16; return c.f;
}
__device__ __forceinline__ void splitstore(float v, u16* ph, u16* pl){
  u16 h = f2bf(v); *ph = h; *pl = f2bf(v - bf2f(h));
}
__device__ __forceinline__ f32x4 MFMA(bf16x8 a, bf16x8 b, f32x4 c){
  return __builtin_amdgcn_mfma_f32_16x16x32_bf16(a, b, c, 0, 0, 0);
}
// async global->LDS, 16B per lane, wave-uniform LDS base (HW adds lane*16)
__device__ __forceinline__ void glds16(const u16* g, u16* l){
  __builtin_amdgcn_global_load_lds(
      (const __attribute__((address_space(1))) void*)g,
      (__attribute__((address_space(3))) void*)l, 16, 0, 0);
}

// system-scope (cross-XCD visible) accesses: sc0 sc1 bypass L1/L2, hit coherent point.
__device__ __forceinline__ void st32_sys(u32* p, u32 v){
  asm volatile("global_store_dword %0, %1, off sc0 sc1" :: "v"(p), "v"(v) : "memory");
}
__device__ __forceinline__ u32 ld32_sys(const u32* p){
  u32 r;
  asm volatile("global_load_dword %0, %1, off sc0 sc1\n\ts_waitcnt vmcnt(0)"
               : "=v"(r) : "v"(p) : "memory");
  return r;
}

// ---------- prep kernels (BN folding, transpose, bf16 hi/lo split) ----------
__global__ __launch_bounds__(256) void k_bn1_split(
    const float* __restrict__ x, const float* __restrict__ g, const float* __restrict__ b,
    const float* __restrict__ m, const float* __restrict__ v,
    u16* __restrict__ oh, u16* __restrict__ ol)
{
  int i = blockIdx.x*256 + threadIdx.x;
  if (i >= 2048000) return;
  int ci = i % 80;
  float s = g[ci] * rsqrtf(v[ci] + EPSBN);
  float val = (x[i] - m[ci]) * s + b[ci];
  splitstore(val, oh+i, ol+i);
}

// conv1 weights -> [co][kf], kf = kw*80+ci, padded K 400->416 with zeros
__global__ __launch_bounds__(256) void k_prep_c1w(
    const float* __restrict__ w0, u16* __restrict__ oh, u16* __restrict__ ol)
{
  int i = blockIdx.x*256 + threadIdx.x;
  if (i >= 512*416) return;
  int co = i / 416, kf = i - co*416;
  float val = 0.f;
  if (kf < 400){ int kw = kf/80, ci = kf - kw*80; val = w0[(kw*80+ci)*512 + co]; }
  splitstore(val, oh+i, ol+i);
}

// conv2 weights -> [co][kf], kf = kw*512+ci  (K=2560)
__global__ __launch_bounds__(256) void k_prep_c2w(
    const float* __restrict__ w1, u16* __restrict__ oh, u16* __restrict__ ol)
{
  int i = blockIdx.x*256 + threadIdx.x;
  if (i >= 5*512*512) return;
  int co = i & 511, ci = (i >> 9) & 511, kw = i >> 18;
  long o = (long)co*2560 + kw*512 + ci;
  splitstore(w1[i], oh+o, ol+o);
}

// gru Wx -> [l*2+d][n][k], BN2 scale folded into layer-0 rows
__global__ __launch_bounds__(256) void k_prep_wx(
    const float* __restrict__ wx, const float* __restrict__ g2, const float* __restrict__ v2,
    u16* __restrict__ oh, u16* __restrict__ ol)
{
  long i = (long)blockIdx.x*256 + threadIdx.x;
  if (i >= 6L*512*1536) return;
  int n = (int)(i % 1536); long r2 = i / 1536; int k = (int)(r2 % 512); int ld = (int)(r2 / 512);
  float s = (ld < 2) ? g2[k]*rsqrtf(v2[k]+EPSBN) : 1.f;
  long o = ((long)ld*1536 + n)*512 + k;
  splitstore(wx[i]*s, oh+o, ol+o);
}

__global__ __launch_bounds__(256) void k_prep_wh(
    const float* __restrict__ wh, u16* __restrict__ oh, u16* __restrict__ ol)
{
  long i = (long)blockIdx.x*256 + threadIdx.x;
  if (i >= 6L*512*1536) return;
  int n = (int)(i % 1536); long r2 = i / 1536; int k = (int)(r2 % 512); int ld = (int)(r2 / 512);
  long o = ((long)ld*1536 + n)*512 + k;
  splitstore(wh[i], oh+o, ol+o);
}

// gru biases: xbias[ld][n] = input bias (+ t2 @ Wx for layer 0), hbias = recurrent bias
__global__ __launch_bounds__(256) void k_prep_grub(
    const float* __restrict__ gb, const float* __restrict__ wx,
    const float* __restrict__ g2, const float* __restrict__ b2,
    const float* __restrict__ m2, const float* __restrict__ v2,
    float* __restrict__ xbias, float* __restrict__ hbias)
{
  int i = blockIdx.x*256 + threadIdx.x;
  if (i >= 6*1536) return;
  int n = i % 1536, ld = i / 1536;
  float xv = gb[(ld*2 + 0)*1536 + n];
  float hv = gb[(ld*2 + 1)*1536 + n];
  if (ld < 2){
    float acc = 0.f;
    for (int k = 0; k < 512; ++k){
      float s = g2[k]*rsqrtf(v2[k]+EPSBN);
      float t = b2[k] - m2[k]*s;
      acc += t * wx[((long)ld*512 + k)*1536 + n];
    }
    xv += acc;
  }
  xbias[i] = xv; hbias[i] = hv;
}

// fc weights with BN3 fold -> [n][k]
__global__ __launch_bounds__(256) void k_prep_fcw(
    const float* __restrict__ fw, const float* __restrict__ g3, const float* __restrict__ v3,
    u16* __restrict__ oh, u16* __restrict__ ol)
{
  int i = blockIdx.x*256 + threadIdx.x;
  if (i >= 512*512) return;
  int n = i & 511, k = i >> 9;
  float s = g3[k]*rsqrtf(v3[k]+EPSBN);
  long o = (long)n*512 + k;
  splitstore(fw[i]*s, oh+o, ol+o);
}

__global__ __launch_bounds__(256) void k_prep_fcb(
    const float* __restrict__ fw, const float* __restrict__ fb,
    const float* __restrict__ g3, const float* __restrict__ b3,
    const float* __restrict__ m3, const float* __restrict__ v3,
    float* __restrict__ ob)
{
  int n = blockIdx.x*256 + threadIdx.x;
  if (n >= 512) return;
  float acc = fb[n];
  for (int k = 0; k < 512; ++k){
    float s = g3[k]*rsqrtf(v3[k]+EPSBN);
    float t = b3[k] - m3[k]*s;
    acc += t * fw[k*512 + n];
  }
  ob[n] = acc;
}

__global__ __launch_bounds__(256) void k_prep_smw(
    const float* __restrict__ sw, u16* __restrict__ oh, u16* __restrict__ ol)
{
  long i = (long)blockIdx.x*256 + threadIdx.x;
  if (i >= 512L*6000) return;
  int n = (int)(i % 6000); int k = (int)(i / 6000);
  long o = (long)n*512 + k;
  splitstore(sw[i], oh+o, ol+o);
}

__global__ __launch_bounds__(256) void k_sumsplit(
    const float* __restrict__ a, const float* __restrict__ b,
    u16* __restrict__ oh, u16* __restrict__ ol)
{
  int i = blockIdx.x*256 + threadIdx.x;
  if (i >= 6352*512) return;
  splitstore(a[i] + b[i], oh+i, ol+i);
}

// ---------- OLD simple GEMM (kept for conv1's 80-wide gather only) ----------
template<int AMODE, int EPI>
__global__ __launch_bounds__(256,1)
void gemm_split(const u16* __restrict__ Ah, const u16* __restrict__ Al,
                const u16* __restrict__ Bh, const u16* __restrict__ Bl,
                const float* __restrict__ bias,
                float* __restrict__ outF, u16* __restrict__ outH, u16* __restrict__ outL,
                int M, int N, int K, int Kvalid, int TIN, int TOUT, int NYB)
{
  constexpr int CW = (AMODE==1) ? 80 : 512;
  const int tid  = threadIdx.x;
  const int lane = tid & 63;
  const int w    = tid >> 6;
  const int wm = w >> 1, wn = w & 1;
  const int r  = lane & 15, kg = lane >> 4;

  const int nwg = gridDim.x;
  const int q   = nwg >> 3;
  const int bid = blockIdx.x;
  const int wg  = (bid & 7) * q + (bid >> 3);
  const int bx  = wg / NYB, by = wg - bx * NYB;

  const int m0 = by * 64 + wm * 32;
  const int n0 = bx * 64 + wn * 32;

  long abase[2];
  #pragma unroll
  for (int mt = 0; mt < 2; ++mt){
    int m = m0 + mt*16 + r;
    int mc = m < M ? m : M - 1;
    if (AMODE == 0) abase[mt] = (long)mc * K;
    else { int bb = mc / TOUT; int tt = mc - bb * TOUT; abase[mt] = ((long)bb * TIN + 2*tt) * CW; }
  }
  long bbase[2];
  #pragma unroll
  for (int nt = 0; nt < 2; ++nt){
    int n = n0 + nt*16 + r;
    int nc = n < N ? n : N - 1;
    bbase[nt] = (long)nc * K;
  }

  f32x4 acc[2][2];
  #pragma unroll
  for (int a_ = 0; a_ < 2; ++a_)
    #pragma unroll
    for (int b_ = 0; b_ < 2; ++b_) acc[a_][b_] = f32x4{0.f,0.f,0.f,0.f};

  const bf16x8 zfrag = {0,0,0,0,0,0,0,0};
  const int koff = kg * 8;
  const int KT = K >> 5;
  for (int kt = 0; kt < KT; ++kt){
    int kf = kt*32 + koff;
    bf16x8 ah[2], al[2], bh[2], bl[2];
    #pragma unroll
    for (int nt = 0; nt < 2; ++nt){
      bh[nt] = *(const bf16x8*)(Bh + bbase[nt] + kf);
      bl[nt] = *(const bf16x8*)(Bl + bbase[nt] + kf);
    }
    #pragma unroll
    for (int mt = 0; mt < 2; ++mt){
      if (kf < Kvalid){
        int kw = kf / CW; int ci = kf - kw*CW;
        long ao = abase[mt] + (long)kw*CW + ci;
        ah[mt] = *(const bf16x8*)(Ah + ao); al[mt] = *(const bf16x8*)(Al + ao);
      } else { ah[mt] = zfrag; al[mt] = zfrag; }
    }
    #pragma unroll
    for (int mt = 0; mt < 2; ++mt)
      #pragma unroll
      for (int nt = 0; nt < 2; ++nt){
        acc[mt][nt] = MFMA(ah[mt], bh[nt], acc[mt][nt]);
        acc[mt][nt] = MFMA(ah[mt], bl[nt], acc[mt][nt]);
        acc[mt][nt] = MFMA(al[mt], bh[nt], acc[mt][nt]);
      }
  }

  #pragma unroll
  for (int nt = 0; nt < 2; ++nt){
    int n = n0 + nt*16 + r;
    if (n >= N) continue;
    float bv = bias ? bias[n] : 0.f;
    #pragma unroll
    for (int mt = 0; mt < 2; ++mt){
      #pragma unroll
      for (int q2 = 0; q2 < 4; ++q2){
        int m = m0 + mt*16 + kg*4 + q2;
        if (m >= M) continue;
        float v = acc[mt][nt][q2] + bv;
        if (EPI == 1) v = fmaxf(v, 0.f);
        if (EPI == 2) v = fminf(fmaxf(v, 0.f), 20.f);
        long o = (long)m * N + n;
        if (EPI == 0) outF[o] = v;
        else { u16 h = f2bf(v); outH[o] = h; outL[o] = f2bf(v - bf2f(h)); }
      }
    }
  }
}

// ---------- NEW: m97-structure GEMM — 128x128 tile, BK=32, global_load_lds ----------
// AMODE 0: A[m][k] direct.  AMODE 2: conv gather (row->abase; BK=32 divides 512 so the
// k-offset collapses to abase + kt*32 — contiguous per row).  B always [N][K].
// 4 waves, 64x64 acc/wave (4x4 frags), split-bf16 3-pass: 48 MFMA : 16 ds_read_b128.
// Staging: 8 glds16 issues/wave/k-step (2 chunks x 4 planes), per-lane clamped src.
template<int AMODE, int EPI>
__global__ __launch_bounds__(256,1)
void gemm_lds(const u16* __restrict__ Ah, const u16* __restrict__ Al,
              const u16* __restrict__ Bh, const u16* __restrict__ Bl,
              const float* __restrict__ bias,
              float* __restrict__ outF, u16* __restrict__ outH, u16* __restrict__ outL,
              int M, int N, int K, int TIN, int TOUT, int NYB, int NTILES)
{
  __shared__ __align__(16) u16 sAh[128*32], sAl[128*32], sBh[128*32], sBl[128*32];

  const int tid  = threadIdx.x;
  const int lane = tid & 63;
  const int w    = tid >> 6;
  const int wm = w >> 1, wn = w & 1;
  const int r  = lane & 15, kg = lane >> 4;

  const int nwg = gridDim.x;
  const int qq  = nwg >> 3;
  const int wg  = (blockIdx.x & 7) * qq + (blockIdx.x >> 3);
  if (wg >= NTILES) return;
  const int bx  = wg / NYB, by = wg - bx * NYB;
  const int m0 = by * 128, n0 = bx * 128;

  // staging descriptors: this wave owns chunks c = 2w, 2w+1 (each 64 lanes x 16B)
  long aoff[2], boff[2]; int cbase[2];
  #pragma unroll
  for (int cc = 0; cc < 2; ++cc){
    int c = w*2 + cc;
    int li = c*64 + lane;
    int row = li >> 2, seg = li & 3;
    cbase[cc] = c*512;                       // u16 offset of chunk in LDS plane
    int ma = m0 + row; if (ma >= M) ma = M - 1;
    if (AMODE == 0) aoff[cc] = (long)ma * K + seg*8;
    else { int bb = ma / TOUT; int tt = ma - bb*TOUT;
           aoff[cc] = ((long)bb * TIN + 2*tt) * 512 + seg*8; }
    int nb = n0 + row; if (nb >= N) nb = N - 1;
    boff[cc] = (long)nb * K + seg*8;
  }

  // fragment read offsets (u16 index into LDS planes)
  int ard[4], brd[4];
  #pragma unroll
  for (int t4 = 0; t4 < 4; ++t4){
    ard[t4] = (wm*64 + t4*16 + r)*32 + kg*8;
    brd[t4] = (wn*64 + t4*16 + r)*32 + kg*8;
  }

  f32x4 acc[4][4];
  #pragma unroll
  for (int i = 0; i < 4; ++i)
    #pragma unroll
    for (int j = 0; j < 4; ++j) acc[i][j] = f32x4{0.f,0.f,0.f,0.f};

  const int KT = K >> 5;
  for (int kt = 0; kt < KT; ++kt){
    const long k32 = (long)kt*32;
    #pragma unroll
    for (int cc = 0; cc < 2; ++cc){
      glds16(Ah + aoff[cc] + k32, sAh + cbase[cc]);
      glds16(Al + aoff[cc] + k32, sAl + cbase[cc]);
      glds16(Bh + boff[cc] + k32, sBh + cbase[cc]);
      glds16(Bl + boff[cc] + k32, sBl + cbase[cc]);
    }
    asm volatile("s_waitcnt vmcnt(0)" ::: "memory");
    __syncthreads();

    bf16x8 ah[4], al[4], bh[4], bl[4];
    #pragma unroll
    for (int t4 = 0; t4 < 4; ++t4){
      ah[t4] = *(const bf16x8*)(sAh + ard[t4]);
      al[t4] = *(const bf16x8*)(sAl + ard[t4]);
      bh[t4] = *(const bf16x8*)(sBh + brd[t4]);
      bl[t4] = *(const bf16x8*)(sBl + brd[t4]);
    }
    #pragma unroll
    for (int i = 0; i < 4; ++i)
      #pragma unroll
      for (int j = 0; j < 4; ++j){
        acc[i][j] = MFMA(ah[i], bh[j], acc[i][j]);
        acc[i][j] = MFMA(ah[i], bl[j], acc[i][j]);
        acc[i][j] = MFMA(al[i], bh[j], acc[i][j]);
      }
    __syncthreads();
  }

  #pragma unroll
  for (int j = 0; j < 4; ++j){
    int n = n0 + wn*64 + j*16 + r;
    if (n >= N) continue;
    float bv = bias ? bias[n] : 0.f;
    #pragma unroll
    for (int i = 0; i < 4; ++i){
      #pragma unroll
      for (int q2 = 0; q2 < 4; ++q2){
        int m = m0 + wm*64 + i*16 + kg*4 + q2;
        if (m >= M) continue;
        float v = acc[i][j][q2] + bv;
        if (EPI == 1) v = fmaxf(v, 0.f);
        if (EPI == 2) v = fminf(fmaxf(v, 0.f), 20.f);
        long o = (long)m * N + n;
        if (EPI == 0) outF[o] = v;
        else { u16 h = f2bf(v); outH[o] = h; outL[o] = f2bf(v - bf2f(h)); }
      }
    }
  }
}

// ---------- persistent bidirectional GRU layer (R10 protocol, at measured floor) ----------
__global__ __launch_bounds__(256,1)
void gru_layer(const float* __restrict__ xp,     // [2][6352][1536]
               const u16* __restrict__ WhH, const u16* __restrict__ WhL, // [2][1536][512]
               const float* __restrict__ hbias,  // [2][1536]
               float* __restrict__ yf, float* __restrict__ yb, // [6352][512] each
               u32* __restrict__ hq,             // [398][2][16][512] u32, time-indexed
               u32* __restrict__ flags,          // [2][32] slots, 64B-strided (16 u32)
               u32 lcode)                        // (layer+1)*1000
{
  const int dir = blockIdx.x >> 5;
  const int s   = blockIdx.x & 31;
  const int tid = threadIdx.x, lane = tid & 63, w = tid >> 6;
  const int r = lane & 15, kg = lane >> 4;

  const float* xpd = xp + (long)dir * (6352L*1536);
  const u16* whh = WhH + (long)dir * (1536L*512);
  const u16* whl = WhL + (long)dir * (1536L*512);
  const float* hb = hbias + dir * 1536;
  float* y = dir ? yb : yf;
  u32* flg = flags + dir * 512;

  __shared__ float red[2][4][3][64][4];

  bf16x8 Bh[3][4], Bl[3][4];
  #pragma unroll
  for (int g = 0; g < 3; ++g){
    long nb = (long)(g*512 + s*16 + r) * 512;
    #pragma unroll
    for (int kk = 0; kk < 4; ++kk){
      int k = (w*4 + kk)*32 + kg*8;
      Bh[g][kk] = *(const bf16x8*)(whh + nb + k);
      Bl[g][kk] = *(const bf16x8*)(whl + nb + k);
    }
  }

  const int gb = tid >> 4, gj = tid & 15;
  const int gcol = s*16 + gj;
  const float bz = hb[gcol], br = hb[512 + gcol], bhh = hb[1024 + gcol];
  const int rl = ((gb >> 2) << 4) | gj;
  const int rq = gb & 3;
  float hreg = 0.f;

  for (int t = 0; t < 397; ++t){
    const int tpos = dir ? (396 - t) : t;
    const long xb_ = ((long)gb*397 + tpos)*1536 + gcol;
    float xz = xpd[xb_], xr = xpd[xb_ + 512], xh = xpd[xb_ + 1024];

    f32x4 a0 = f32x4{0.f,0.f,0.f,0.f}, a1 = a0, a2 = a0;
    if (t > 0){
      if (w == 0){
        const u32 tgt = lcode + (u32)t;
        for (;;){
          int done = 1;
          if (lane < 32) done = (ld32_sys(flg + lane*16) >= tgt);
          if (__all(done)) break;
        }
      }
      __syncthreads();

      const u32* hqs = hq + ((long)t*2 + dir) * 8192;
      const int cbase2 = r*512 + kg*8;
      u32x4 q0[4], q1[4];
      #pragma unroll
      for (int kk = 0; kk < 4; ++kk){
        const u32x4* pp = (const u32x4*)(hqs + cbase2 + (w*4 + kk)*32);
        q0[kk] = pp[0]; q1[kk] = pp[1];
      }

      bf16x8 ah[4], al[4];
      #pragma unroll
      for (int kk = 0; kk < 4; ++kk){
        union { bf16x8 v; u32 u[4]; } A, L;
        A.u[0] = __builtin_amdgcn_perm(q0[kk].y, q0[kk].x, 0x07060302u);
        L.u[0] = __builtin_amdgcn_perm(q0[kk].y, q0[kk].x, 0x05040100u);
        A.u[1] = __builtin_amdgcn_perm(q0[kk].w, q0[kk].z, 0x07060302u);
        L.u[1] = __builtin_amdgcn_perm(q0[kk].w, q0[kk].z, 0x05040100u);
        A.u[2] = __builtin_amdgcn_perm(q1[kk].y, q1[kk].x, 0x07060302u);
        L.u[2] = __builtin_amdgcn_perm(q1[kk].y, q1[kk].x, 0x05040100u);
        A.u[3] = __builtin_amdgcn_perm(q1[kk].w, q1[kk].z, 0x07060302u);
        L.u[3] = __builtin_amdgcn_perm(q1[kk].w, q1[kk].z, 0x05040100u);
        ah[kk] = A.v; al[kk] = L.v;
      }
      #pragma unroll
      for (int kk = 0; kk < 4; ++kk){
        a0 = MFMA(ah[kk], Bh[0][kk], a0); a0 = MFMA(ah[kk], Bl[0][kk], a0); a0 = MFMA(al[kk], Bh[0][kk], a0);
        a1 = MFMA(ah[kk], Bh[1][kk], a1); a1 = MFMA(ah[kk], Bl[1][kk], a1); a1 = MFMA(al[kk], Bh[1][kk], a1);
        a2 = MFMA(ah[kk], Bh[2][kk], a2); a2 = MFMA(ah[kk], Bl[2][kk], a2); a2 = MFMA(al[kk], Bh[2][kk], a2);
      }
    }
    const int tb = t & 1;
    *(f32x4*)&red[tb][w][0][lane][0] = a0;
    *(f32x4*)&red[tb][w][1][lane][0] = a1;
    *(f32x4*)&red[tb][w][2][lane][0] = a2;
    __syncthreads();
    float rz = bz, rr = br, rh = bhh;
    #pragma unroll
    for (int ww = 0; ww < 4; ++ww){
      rz += red[tb][ww][0][rl][rq];
      rr += red[tb][ww][1][rl][rq];
      rh += red[tb][ww][2][rl][rq];
    }
    float z  = 1.f / (1.f + __expf(-(xz + rz)));
    float rg = 1.f / (1.f + __expf(-(xr + rr)));
    float hh = fmaxf(xh + rg * rh, 0.f);
    hreg = z * hreg + (1.f - z) * hh;

    {
      u32* o = hq + ((long)(t+1)*2 + dir) * 8192 + gb*512 + gcol;
      u16 hi = f2bf(hreg); u16 lo = f2bf(hreg - bf2f(hi));
      st32_sys(o, ((u32)hi << 16) | (u32)lo);
    }
    asm volatile("s_waitcnt vmcnt(0)" ::: "memory");
    __syncthreads();
    if (tid == 0) st32_sys(flg + s*16, lcode + (u32)(t + 1));
    y[((long)gb*397 + tpos)*512 + gcol] = hreg;
  }
}

// ---------- in-place row softmax on d_out [6352][6000] ----------
__global__ __launch_bounds__(256,1) void k_softmax(float* __restrict__ out)
{
  const int tid = threadIdx.x;
  float* prow = out + (long)blockIdx.x * 6000;
  float vals[24];
  float mx = -3.0e38f;
  #pragma unroll
  for (int i = 0; i < 24; ++i){
    int idx = tid + i*256;
    vals[i] = (idx < 6000) ? prow[idx] : -3.0e38f;
    mx = fmaxf(mx, vals[i]);
  }
  #pragma unroll
  for (int o = 32; o; o >>= 1) mx = fmaxf(mx, __shfl_xor(mx, o));
  __shared__ float sred[4];
  if ((tid & 63) == 0) sred[tid >> 6] = mx;
  __syncthreads();
  mx = fmaxf(fmaxf(sred[0], sred[1]), fmaxf(sred[2], sred[3]));
  __syncthreads();
  float sum = 0.f;
  #pragma unroll
  for (int i = 0; i < 24; ++i){
    int idx = tid + i*256;
    vals[i] = (idx < 6000) ? expf(vals[i] - mx) : 0.f;
    sum += vals[i];
  }
  #pragma unroll
  for (int o = 32; o; o >>= 1) sum += __shfl_xor(sum, o);
  if ((tid & 63) == 0) sred[tid >> 6] = sum;
  __syncthreads();
  sum = sred[0] + sred[1] + sred[2] + sred[3];
  float inv = 1.f / sum;
  #pragma unroll
  for (int i = 0; i < 24; ++i){
    int idx = tid + i*256;
    if (idx < 6000) prow[idx] = vals[i] * inv;
  }
}

// ---------- host ----------
extern "C" void kernel_launch(void* const* d_in, const int* in_sizes, int n_in,
                              void* d_out, int out_size, void* d_ws, size_t ws_size,
                              hipStream_t stream)
{
  (void)in_sizes; (void)n_in; (void)out_size; (void)ws_size;
  const float* x    = (const float*)d_in[0];
  const float* bn1g = (const float*)d_in[1];
  const float* bn1b = (const float*)d_in[2];
  const float* bn1m = (const float*)d_in[3];
  const float* bn1v = (const float*)d_in[4];
  const float* cw0  = (const float*)d_in[5];
  const float* cb0  = (const float*)d_in[6];
  const float* cw1  = (const float*)d_in[7];
  const float* cb1  = (const float*)d_in[8];
  const float* bn2g = (const float*)d_in[9];
  const float* bn2b = (const float*)d_in[10];
  const float* bn2m = (const float*)d_in[11];
  const float* bn2v = (const float*)d_in[12];
  const float* gwx  = (const float*)d_in[13];
  const float* gwh  = (const float*)d_in[14];
  const float* gbia = (const float*)d_in[15];
  const float* bn3g = (const float*)d_in[16];
  const float* bn3b = (const float*)d_in[17];
  const float* bn3m = (const float*)d_in[18];
  const float* bn3v = (const float*)d_in[19];
  const float* fcw  = (const float*)d_in[20];
  const float* fcb  = (const float*)d_in[21];
  const float* smw  = (const float*)d_in[22];
  const float* smb  = (const float*)d_in[23];

  char* p = (char*)d_ws;
  auto alloc = [&](size_t bytes)->char*{
    char* q = p; p += (bytes + 255) & ~(size_t)255; return q;
  };
  const size_t NX=2048000, NC1W=512*416, NC1O=12768L*512, NC2W=512*2560,
               NC2O=6352L*512, NWX=6L*1536*512, NXP=2L*6352*1536,
               NSMW=6000L*512, NFCW=512*512;

  u16 *xbnH=(u16*)alloc(NX*2),  *xbnL=(u16*)alloc(NX*2);
  u16 *c1wH=(u16*)alloc(NC1W*2),*c1wL=(u16*)alloc(NC1W*2);
  u16 *c1oH=(u16*)alloc(NC1O*2),*c1oL=(u16*)alloc(NC1O*2);
  u16 *c2wH=(u16*)alloc(NC2W*2),*c2wL=(u16*)alloc(NC2W*2);
  u16 *c2oH=(u16*)alloc(NC2O*2),*c2oL=(u16*)alloc(NC2O*2);
  u16 *wxH=(u16*)alloc(NWX*2),  *wxL=(u16*)alloc(NWX*2);
  u16 *whH=(u16*)alloc(NWX*2),  *whL=(u16*)alloc(NWX*2);
  float *xbias=(float*)alloc(6*1536*4), *hbias=(float*)alloc(6*1536*4);
  float *xp=(float*)alloc(NXP*4);
  float *yf=(float*)alloc(NC2O*4), *yb=(float*)alloc(NC2O*4);
  u16 *ysH=(u16*)alloc(NC2O*2), *ysL=(u16*)alloc(NC2O*2);
  u16 *fcwH=(u16*)alloc(NFCW*2),*fcwL=(u16*)alloc(NFCW*2);
  float *fcb2=(float*)alloc(512*4);
  u16 *fcoH=(u16*)alloc(NC2O*2),*fcoL=(u16*)alloc(NC2O*2);
  u16 *smwH=(u16*)alloc(NSMW*2),*smwL=(u16*)alloc(NSMW*2);
  u32 *hq=(u32*)alloc(398L*2*8192*4);
  u32 *flags=(u32*)alloc(2*512*4);

  hipMemsetAsync(flags, 0, 2*512*4, stream);

  k_bn1_split<<<8000,256,0,stream>>>(x, bn1g,bn1b,bn1m,bn1v, xbnH,xbnL);
  k_prep_c1w <<<832,256,0,stream>>>(cw0, c1wH,c1wL);
  k_prep_c2w <<<5120,256,0,stream>>>(cw1, c2wH,c2wL);
  k_prep_wx  <<<18432,256,0,stream>>>(gwx, bn2g,bn2v, wxH,wxL);
  k_prep_wh  <<<18432,256,0,stream>>>(gwh, whH,whL);
  k_prep_grub<<<36,256,0,stream>>>(gbia, gwx, bn2g,bn2b,bn2m,bn2v, xbias,hbias);
  k_prep_fcw <<<1024,256,0,stream>>>(fcw, bn3g,bn3v, fcwH,fcwL);
  k_prep_fcb <<<2,256,0,stream>>>(fcw,fcb, bn3g,bn3b,bn3m,bn3v, fcb2);
  k_prep_smw <<<12000,256,0,stream>>>(smw, smwH,smwL);

  // conv1 (80-wide gather): old path. M=12768,N=512,K=416(valid 400); grid 1600, NYB=200
  gemm_split<1,1><<<1600,256,0,stream>>>(xbnH,xbnL, c1wH,c1wL, cb0,
      nullptr, c1oH,c1oL, 12768,512,416, 400, 1600,798, 200);
  // conv2 (m97 path, AMODE2): M=6352,N=512,K=2560; tiles 4x50=200
  gemm_lds<2,1><<<200,256,0,stream>>>(c1oH,c1oL, c2wH,c2wL, cb1,
      nullptr, c2oH,c2oL, 6352,512,2560, 798,397, 50, 200);

  const u16 *aH = c2oH, *aL = c2oL;
  for (int l = 0; l < 3; ++l){
    for (int d = 0; d < 2; ++d){
      // xp: M=6352,N=1536,K=512; tiles 12x50=600
      gemm_lds<0,0><<<600,256,0,stream>>>(aH,aL,
          wxH + (size_t)(l*2+d)*786432, wxL + (size_t)(l*2+d)*786432,
          xbias + (l*2+d)*1536,
          xp + (size_t)d*9756672, nullptr,nullptr,
          6352,1536,512, 0,0, 50, 600);
    }
    gru_layer<<<64,256,0,stream>>>(xp,
        whH + (size_t)l*2*786432, whL + (size_t)l*2*786432,
        hbias + l*2*1536, yf,yb, hq, flags, (u32)((l+1)*1000));
    k_sumsplit<<<12704,256,0,stream>>>(yf,yb, ysH,ysL);
    aH = ysH; aL = ysL;
  }

  // fc: M=6352,N=512,K=512; tiles 4x50=200
  gemm_lds<0,2><<<200,256,0,stream>>>(ysH,ysL, fcwH,fcwL, fcb2,
      nullptr, fcoH,fcoL, 6352,512,512, 0,0, 50, 200);
  // logits: M=6352,N=6000,K=512; tiles 47x50=2350 -> grid padded to 2352 (div 8)
  gemm_lds<0,0><<<2352,256,0,stream>>>(fcoH,fcoL, smwH,smwL, smb,
      (float*)d_out, nullptr,nullptr, 6352,6000,512, 0,0, 50, 2350);
  k_softmax<<<6352,256,0,stream>>>((float*)d_out);
}

// Round 13
// 4796.110 us; speedup vs baseline: 1.4717x; 1.0365x over previous
//
#include <hip/hip_runtime.h>
#include <math.h>

// ---------- types / helpers ----------
using bf16x8 = __attribute__((ext_vector_type(8))) short;
using f32x4  = __attribute__((ext_vector_type(4))) float;
using u32x4  = __attribute__((ext_vector_type(4))) unsigned int;
typedef unsigned short u16;
typedef unsigned int   u32;

#define EPSBN 1e-3f

__device__ __forceinline__ u16 f2bf(float f){
  union { float f; u32 u; } c; c.f = f;
  u32 u = c.u + 0x7fffu + ((c.u >> 16) & 1u);
  return (u16)(u >> 16);
}
__device__ __forceinline__ float bf2f(u16 b){
  union { u32 u; float f; } c; c.u = ((u32)b) << 16; return c.f;
}
__device__ __forceinline__ void splitstore(float v, u16* ph, u16* pl){
  u16 h = f2bf(v); *ph = h; *pl = f2bf(v - bf2f(h));
}
__device__ __forceinline__ f32x4 MFMA(bf16x8 a, bf16x8 b, f32x4 c){
  return __builtin_amdgcn_mfma_f32_16x16x32_bf16(a, b, c, 0, 0, 0);
}
// async global->LDS, 16B per lane, wave-uniform LDS base (HW adds lane*16)
__device__ __forceinline__ void glds16(const u16* g, u16* l){
  __builtin_amdgcn_global_load_lds(
      (const __attribute__((address_space(1))) void*)g,
      (__attribute__((address_space(3))) void*)l, 16, 0, 0);
}

// system-scope (cross-XCD visible) accesses: sc0 sc1 bypass L1/L2, hit coherent point.
__device__ __forceinline__ void st32_sys(u32* p, u32 v){
  asm volatile("global_store_dword %0, %1, off sc0 sc1" :: "v"(p), "v"(v) : "memory");
}
__device__ __forceinline__ u32 ld32_sys(const u32* p){
  u32 r;
  asm volatile("global_load_dword %0, %1, off sc0 sc1\n\ts_waitcnt vmcnt(0)"
               : "=v"(r) : "v"(p) : "memory");
  return r;
}

// ---------- prep kernels (BN folding, transpose, bf16 hi/lo split) ----------
__global__ __launch_bounds__(256) void k_bn1_split(
    const float* __restrict__ x, const float* __restrict__ g, const float* __restrict__ b,
    const float* __restrict__ m, const float* __restrict__ v,
    u16* __restrict__ oh, u16* __restrict__ ol)
{
  int i = blockIdx.x*256 + threadIdx.x;
  if (i >= 2048000) return;
  int ci = i % 80;
  float s = g[ci] * rsqrtf(v[ci] + EPSBN);
  float val = (x[i] - m[ci]) * s + b[ci];
  splitstore(val, oh+i, ol+i);
}

// conv1 weights -> [co][kf], kf = kw*80+ci, padded K 400->416 with zeros
__global__ __launch_bounds__(256) void k_prep_c1w(
    const float* __restrict__ w0, u16* __restrict__ oh, u16* __restrict__ ol)
{
  int i = blockIdx.x*256 + threadIdx.x;
  if (i >= 512*416) return;
  int co = i / 416, kf = i - co*416;
  float val = 0.f;
  if (kf < 400){ int kw = kf/80, ci = kf - kw*80; val = w0[(kw*80+ci)*512 + co]; }
  splitstore(val, oh+i, ol+i);
}

// conv2 weights -> [co][kf], kf = kw*512+ci  (K=2560)
__global__ __launch_bounds__(256) void k_prep_c2w(
    const float* __restrict__ w1, u16* __restrict__ oh, u16* __restrict__ ol)
{
  int i = blockIdx.x*256 + threadIdx.x;
  if (i >= 5*512*512) return;
  int co = i & 511, ci = (i >> 9) & 511, kw = i >> 18;
  long o = (long)co*2560 + kw*512 + ci;
  splitstore(w1[i], oh+o, ol+o);
}

// gru Wx -> [l*2+d][n][k], BN2 scale folded into layer-0 rows
__global__ __launch_bounds__(256) void k_prep_wx(
    const float* __restrict__ wx, const float* __restrict__ g2, const float* __restrict__ v2,
    u16* __restrict__ oh, u16* __restrict__ ol)
{
  long i = (long)blockIdx.x*256 + threadIdx.x;
  if (i >= 6L*512*1536) return;
  int n = (int)(i % 1536); long r2 = i / 1536; int k = (int)(r2 % 512); int ld = (int)(r2 / 512);
  float s = (ld < 2) ? g2[k]*rsqrtf(v2[k]+EPSBN) : 1.f;
  long o = ((long)ld*1536 + n)*512 + k;
  splitstore(wx[i]*s, oh+o, ol+o);
}

__global__ __launch_bounds__(256) void k_prep_wh(
    const float* __restrict__ wh, u16* __restrict__ oh, u16* __restrict__ ol)
{
  long i = (long)blockIdx.x*256 + threadIdx.x;
  if (i >= 6L*512*1536) return;
  int n = (int)(i % 1536); long r2 = i / 1536; int k = (int)(r2 % 512); int ld = (int)(r2 / 512);
  long o = ((long)ld*1536 + n)*512 + k;
  splitstore(wh[i], oh+o, ol+o);
}

// gru biases: xbias[ld][n] = input bias (+ t2 @ Wx for layer 0), hbias = recurrent bias
__global__ __launch_bounds__(256) void k_prep_grub(
    const float* __restrict__ gb, const float* __restrict__ wx,
    const float* __restrict__ g2, const float* __restrict__ b2,
    const float* __restrict__ m2, const float* __restrict__ v2,
    float* __restrict__ xbias, float* __restrict__ hbias)
{
  int i = blockIdx.x*256 + threadIdx.x;
  if (i >= 6*1536) return;
  int n = i % 1536, ld = i / 1536;
  float xv = gb[(ld*2 + 0)*1536 + n];
  float hv = gb[(ld*2 + 1)*1536 + n];
  if (ld < 2){
    float acc = 0.f;
    for (int k = 0; k < 512; ++k){
      float s = g2[k]*rsqrtf(v2[k]+EPSBN);
      float t = b2[k] - m2[k]*s;
      acc += t * wx[((long)ld*512 + k)*1536 + n];
    }
    xv += acc;
  }
  xbias[i] = xv; hbias[i] = hv;
}

// fc weights with BN3 fold -> [n][k]
__global__ __launch_bounds__(256) void k_prep_fcw(
    const float* __restrict__ fw, const float* __restrict__ g3, const float* __restrict__ v3,
    u16* __restrict__ oh, u16* __restrict__ ol)
{
  int i = blockIdx.x*256 + threadIdx.x;
  if (i >= 512*512) return;
  int n = i & 511, k = i >> 9;
  float s = g3[k]*rsqrtf(v3[k]+EPSBN);
  long o = (long)n*512 + k;
  splitstore(fw[i]*s, oh+o, ol+o);
}

__global__ __launch_bounds__(256) void k_prep_fcb(
    const float* __restrict__ fw, const float* __restrict__ fb,
    const float* __restrict__ g3, const float* __restrict__ b3,
    const float* __restrict__ m3, const float* __restrict__ v3,
    float* __restrict__ ob)
{
  int n = blockIdx.x*256 + threadIdx.x;
  if (n >= 512) return;
  float acc = fb[n];
  for (int k = 0; k < 512; ++k){
    float s = g3[k]*rsqrtf(v3[k]+EPSBN);
    float t = b3[k] - m3[k]*s;
    acc += t * fw[k*512 + n];
  }
  ob[n] = acc;
}

__global__ __launch_bounds__(256) void k_prep_smw(
    const float* __restrict__ sw, u16* __restrict__ oh, u16* __restrict__ ol)
{
  long i = (long)blockIdx.x*256 + threadIdx.x;
  if (i >= 512L*6000) return;
  int n = (int)(i % 6000); int k = (int)(i / 6000);
  long o = (long)n*512 + k;
  splitstore(sw[i], oh+o, ol+o);
}

__global__ __launch_bounds__(256) void k_sumsplit(
    const float* __restrict__ a, const float* __restrict__ b,
    u16* __restrict__ oh, u16* __restrict__ ol)
{
  int i = blockIdx.x*256 + threadIdx.x;
  if (i >= 6352*512) return;
  splitstore(a[i] + b[i], oh+i, ol+i);
}

// ---------- m97-structure GEMM — 128x128 tile, BK=32, global_load_lds ----------
// CW=0: A[m][k] direct.  CW>0: strided conv gather — source addr is LINEAR in kf
// (addr = abase + kf) because consecutive kw advance source by CW = kf by CW, and
// CW % 8 == 0 means no 16B chunk straddles a window boundary. Pad columns read
// in-bounds garbage x zero-padded weights = 0.
// 4 waves, 64x64 acc/wave (4x4 frags), split-bf16 3-pass: 48 MFMA : 16 ds_read_b128.
// __launch_bounds__(256,2): 2 blocks/CU (64KB LDS), better latency hiding on short-K.
template<int CW, int EPI>
__global__ __launch_bounds__(256,2)
void gemm_lds(const u16* __restrict__ Ah, const u16* __restrict__ Al,
              const u16* __restrict__ Bh, const u16* __restrict__ Bl,
              const float* __restrict__ bias,
              float* __restrict__ outF, u16* __restrict__ outH, u16* __restrict__ outL,
              int M, int N, int K, int TIN, int TOUT, int NYB, int NTILES)
{
  __shared__ __align__(16) u16 sAh[128*32], sAl[128*32], sBh[128*32], sBl[128*32];

  const int tid  = threadIdx.x;
  const int lane = tid & 63;
  const int w    = tid >> 6;
  const int wm = w >> 1, wn = w & 1;
  const int r  = lane & 15, kg = lane >> 4;

  const int nwg = gridDim.x;
  const int qq  = nwg >> 3;
  const int wg  = (blockIdx.x & 7) * qq + (blockIdx.x >> 3);
  if (wg >= NTILES) return;
  const int bx  = wg / NYB, by = wg - bx * NYB;
  const int m0 = by * 128, n0 = bx * 128;

  // staging descriptors: this wave owns chunks c = 2w, 2w+1 (each 64 lanes x 16B)
  long aoff[2], boff[2]; int cbase[2];
  #pragma unroll
  for (int cc = 0; cc < 2; ++cc){
    int c = w*2 + cc;
    int li = c*64 + lane;
    int row = li >> 2, seg = li & 3;
    cbase[cc] = c*512;                       // u16 offset of chunk in LDS plane
    int ma = m0 + row; if (ma >= M) ma = M - 1;
    if (CW == 0) aoff[cc] = (long)ma * K + seg*8;
    else { int bb = ma / TOUT; int tt = ma - bb*TOUT;
           aoff[cc] = ((long)bb * TIN + 2*tt) * CW + seg*8; }
    int nb = n0 + row; if (nb >= N) nb = N - 1;
    boff[cc] = (long)nb * K + seg*8;
  }

  // fragment read offsets (u16 index into LDS planes)
  int ard[4], brd[4];
  #pragma unroll
  for (int t4 = 0; t4 < 4; ++t4){
    ard[t4] = (wm*64 + t4*16 + r)*32 + kg*8;
    brd[t4] = (wn*64 + t4*16 + r)*32 + kg*8;
  }

  f32x4 acc[4][4];
  #pragma unroll
  for (int i = 0; i < 4; ++i)
    #pragma unroll
    for (int j = 0; j < 4; ++j) acc[i][j] = f32x4{0.f,0.f,0.f,0.f};

  const int KT = K >> 5;
  for (int kt = 0; kt < KT; ++kt){
    const long k32 = (long)kt*32;
    #pragma unroll
    for (int cc = 0; cc < 2; ++cc){
      glds16(Ah + aoff[cc] + k32, sAh + cbase[cc]);
      glds16(Al + aoff[cc] + k32, sAl + cbase[cc]);
      glds16(Bh + boff[cc] + k32, sBh + cbase[cc]);
      glds16(Bl + boff[cc] + k32, sBl + cbase[cc]);
    }
    asm volatile("s_waitcnt vmcnt(0)" ::: "memory");
    __syncthreads();

    bf16x8 ah[4], al[4], bh[4], bl[4];
    #pragma unroll
    for (int t4 = 0; t4 < 4; ++t4){
      ah[t4] = *(const bf16x8*)(sAh + ard[t4]);
      al[t4] = *(const bf16x8*)(sAl + ard[t4]);
      bh[t4] = *(const bf16x8*)(sBh + brd[t4]);
      bl[t4] = *(const bf16x8*)(sBl + brd[t4]);
    }
    #pragma unroll
    for (int i = 0; i < 4; ++i)
      #pragma unroll
      for (int j = 0; j < 4; ++j){
        acc[i][j] = MFMA(ah[i], bh[j], acc[i][j]);
        acc[i][j] = MFMA(ah[i], bl[j], acc[i][j]);
        acc[i][j] = MFMA(al[i], bh[j], acc[i][j]);
      }
    __syncthreads();
  }

  #pragma unroll
  for (int j = 0; j < 4; ++j){
    int n = n0 + wn*64 + j*16 + r;
    if (n >= N) continue;
    float bv = bias ? bias[n] : 0.f;
    #pragma unroll
    for (int i = 0; i < 4; ++i){
      #pragma unroll
      for (int q2 = 0; q2 < 4; ++q2){
        int m = m0 + wm*64 + i*16 + kg*4 + q2;
        if (m >= M) continue;
        float v = acc[i][j][q2] + bv;
        if (EPI == 1) v = fmaxf(v, 0.f);
        if (EPI == 2) v = fminf(fmaxf(v, 0.f), 20.f);
        long o = (long)m * N + n;
        if (EPI == 0) outF[o] = v;
        else { u16 h = f2bf(v); outH[o] = h; outL[o] = f2bf(v - bf2f(h)); }
      }
    }
  }
}

// ---------- persistent bidirectional GRU layer (R10 protocol, at measured floor) ----------
// xp is now the FUSED [6352][3072] buffer: dir0 gates at cols 0-1535, dir1 at 1536-3071.
__global__ __launch_bounds__(256,1)
void gru_layer(const float* __restrict__ xp,     // [6352][3072]
               const u16* __restrict__ WhH, const u16* __restrict__ WhL, // [2][1536][512]
               const float* __restrict__ hbias,  // [2][1536]
               float* __restrict__ yf, float* __restrict__ yb, // [6352][512] each
               u32* __restrict__ hq,             // [398][2][16][512] u32, time-indexed
               u32* __restrict__ flags,          // [2][32] slots, 64B-strided (16 u32)
               u32 lcode)                        // (layer+1)*1000
{
  const int dir = blockIdx.x >> 5;
  const int s   = blockIdx.x & 31;
  const int tid = threadIdx.x, lane = tid & 63, w = tid >> 6;
  const int r = lane & 15, kg = lane >> 4;

  const float* xpd = xp + dir * 1536;
  const u16* whh = WhH + (long)dir * (1536L*512);
  const u16* whl = WhL + (long)dir * (1536L*512);
  const float* hb = hbias + dir * 1536;
  float* y = dir ? yb : yf;
  u32* flg = flags + dir * 512;

  __shared__ float red[2][4][3][64][4];

  bf16x8 Bh[3][4], Bl[3][4];
  #pragma unroll
  for (int g = 0; g < 3; ++g){
    long nb = (long)(g*512 + s*16 + r) * 512;
    #pragma unroll
    for (int kk = 0; kk < 4; ++kk){
      int k = (w*4 + kk)*32 + kg*8;
      Bh[g][kk] = *(const bf16x8*)(whh + nb + k);
      Bl[g][kk] = *(const bf16x8*)(whl + nb + k);
    }
  }

  const int gb = tid >> 4, gj = tid & 15;
  const int gcol = s*16 + gj;
  const float bz = hb[gcol], br = hb[512 + gcol], bhh = hb[1024 + gcol];
  const int rl = ((gb >> 2) << 4) | gj;
  const int rq = gb & 3;
  float hreg = 0.f;

  for (int t = 0; t < 397; ++t){
    const int tpos = dir ? (396 - t) : t;
    const long xb_ = ((long)gb*397 + tpos)*3072 + gcol;
    float xz = xpd[xb_], xr = xpd[xb_ + 512], xh = xpd[xb_ + 1024];

    f32x4 a0 = f32x4{0.f,0.f,0.f,0.f}, a1 = a0, a2 = a0;
    if (t > 0){
      if (w == 0){
        const u32 tgt = lcode + (u32)t;
        for (;;){
          int done = 1;
          if (lane < 32) done = (ld32_sys(flg + lane*16) >= tgt);
          if (__all(done)) break;
        }
      }
      __syncthreads();

      const u32* hqs = hq + ((long)t*2 + dir) * 8192;
      const int cbase2 = r*512 + kg*8;
      u32x4 q0[4], q1[4];
      #pragma unroll
      for (int kk = 0; kk < 4; ++kk){
        const u32x4* pp = (const u32x4*)(hqs + cbase2 + (w*4 + kk)*32);
        q0[kk] = pp[0]; q1[kk] = pp[1];
      }

      bf16x8 ah[4], al[4];
      #pragma unroll
      for (int kk = 0; kk < 4; ++kk){
        union { bf16x8 v; u32 u[4]; } A, L;
        A.u[0] = __builtin_amdgcn_perm(q0[kk].y, q0[kk].x, 0x07060302u);
        L.u[0] = __builtin_amdgcn_perm(q0[kk].y, q0[kk].x, 0x05040100u);
        A.u[1] = __builtin_amdgcn_perm(q0[kk].w, q0[kk].z, 0x07060302u);
        L.u[1] = __builtin_amdgcn_perm(q0[kk].w, q0[kk].z, 0x05040100u);
        A.u[2] = __builtin_amdgcn_perm(q1[kk].y, q1[kk].x, 0x07060302u);
        L.u[2] = __builtin_amdgcn_perm(q1[kk].y, q1[kk].x, 0x05040100u);
        A.u[3] = __builtin_amdgcn_perm(q1[kk].w, q1[kk].z, 0x07060302u);
        L.u[3] = __builtin_amdgcn_perm(q1[kk].w, q1[kk].z, 0x05040100u);
        ah[kk] = A.v; al[kk] = L.v;
      }
      #pragma unroll
      for (int kk = 0; kk < 4; ++kk){
        a0 = MFMA(ah[kk], Bh[0][kk], a0); a0 = MFMA(ah[kk], Bl[0][kk], a0); a0 = MFMA(al[kk], Bh[0][kk], a0);
        a1 = MFMA(ah[kk], Bh[1][kk], a1); a1 = MFMA(ah[kk], Bl[1][kk], a1); a1 = MFMA(al[kk], Bh[1][kk], a1);
        a2 = MFMA(ah[kk], Bh[2][kk], a2); a2 = MFMA(ah[kk], Bl[2][kk], a2); a2 = MFMA(al[kk], Bh[2][kk], a2);
      }
    }
    const int tb = t & 1;
    *(f32x4*)&red[tb][w][0][lane][0] = a0;
    *(f32x4*)&red[tb][w][1][lane][0] = a1;
    *(f32x4*)&red[tb][w][2][lane][0] = a2;
    __syncthreads();
    float rz = bz, rr = br, rh = bhh;
    #pragma unroll
    for (int ww = 0; ww < 4; ++ww){
      rz += red[tb][ww][0][rl][rq];
      rr += red[tb][ww][1][rl][rq];
      rh += red[tb][ww][2][rl][rq];
    }
    float z  = 1.f / (1.f + __expf(-(xz + rz)));
    float rg = 1.f / (1.f + __expf(-(xr + rr)));
    float hh = fmaxf(xh + rg * rh, 0.f);
    hreg = z * hreg + (1.f - z) * hh;

    {
      u32* o = hq + ((long)(t+1)*2 + dir) * 8192 + gb*512 + gcol;
      u16 hi = f2bf(hreg); u16 lo = f2bf(hreg - bf2f(hi));
      st32_sys(o, ((u32)hi << 16) | (u32)lo);
    }
    asm volatile("s_waitcnt vmcnt(0)" ::: "memory");
    __syncthreads();
    if (tid == 0) st32_sys(flg + s*16, lcode + (u32)(t + 1));
    y[((long)gb*397 + tpos)*512 + gcol] = hreg;
  }
}

// ---------- in-place row softmax on d_out [6352][6000] ----------
__global__ __launch_bounds__(256,1) void k_softmax(float* __restrict__ out)
{
  const int tid = threadIdx.x;
  float* prow = out + (long)blockIdx.x * 6000;
  float vals[24];
  float mx = -3.0e38f;
  #pragma unroll
  for (int i = 0; i < 24; ++i){
    int idx = tid + i*256;
    vals[i] = (idx < 6000) ? prow[idx] : -3.0e38f;
    mx = fmaxf(mx, vals[i]);
  }
  #pragma unroll
  for (int o = 32; o; o >>= 1) mx = fmaxf(mx, __shfl_xor(mx, o));
  __shared__ float sred[4];
  if ((tid & 63) == 0) sred[tid >> 6] = mx;
  __syncthreads();
  mx = fmaxf(fmaxf(sred[0], sred[1]), fmaxf(sred[2], sred[3]));
  __syncthreads();
  float sum = 0.f;
  #pragma unroll
  for (int i = 0; i < 24; ++i){
    int idx = tid + i*256;
    vals[i] = (idx < 6000) ? expf(vals[i] - mx) : 0.f;
    sum += vals[i];
  }
  #pragma unroll
  for (int o = 32; o; o >>= 1) sum += __shfl_xor(sum, o);
  if ((tid & 63) == 0) sred[tid >> 6] = sum;
  __syncthreads();
  sum = sred[0] + sred[1] + sred[2] + sred[3];
  float inv = 1.f / sum;
  #pragma unroll
  for (int i = 0; i < 24; ++i){
    int idx = tid + i*256;
    if (idx < 6000) prow[idx] = vals[i] * inv;
  }
}

// ---------- host ----------
extern "C" void kernel_launch(void* const* d_in, const int* in_sizes, int n_in,
                              void* d_out, int out_size, void* d_ws, size_t ws_size,
                              hipStream_t stream)
{
  (void)in_sizes; (void)n_in; (void)out_size; (void)ws_size;
  const float* x    = (const float*)d_in[0];
  const float* bn1g = (const float*)d_in[1];
  const float* bn1b = (const float*)d_in[2];
  const float* bn1m = (const float*)d_in[3];
  const float* bn1v = (const float*)d_in[4];
  const float* cw0  = (const float*)d_in[5];
  const float* cb0  = (const float*)d_in[6];
  const float* cw1  = (const float*)d_in[7];
  const float* cb1  = (const float*)d_in[8];
  const float* bn2g = (const float*)d_in[9];
  const float* bn2b = (const float*)d_in[10];
  const float* bn2m = (const float*)d_in[11];
  const float* bn2v = (const float*)d_in[12];
  const float* gwx  = (const float*)d_in[13];
  const float* gwh  = (const float*)d_in[14];
  const float* gbia = (const float*)d_in[15];
  const float* bn3g = (const float*)d_in[16];
  const float* bn3b = (const float*)d_in[17];
  const float* bn3m = (const float*)d_in[18];
  const float* bn3v = (const float*)d_in[19];
  const float* fcw  = (const float*)d_in[20];
  const float* fcb  = (const float*)d_in[21];
  const float* smw  = (const float*)d_in[22];
  const float* smb  = (const float*)d_in[23];

  char* p = (char*)d_ws;
  auto alloc = [&](size_t bytes)->char*{
    char* q = p; p += (bytes + 255) & ~(size_t)255; return q;
  };
  const size_t NX=2048000, NC1W=512*416, NC1O=12768L*512, NC2W=512*2560,
               NC2O=6352L*512, NWX=6L*1536*512, NXP=6352L*3072,
               NSMW=6000L*512, NFCW=512*512;

  u16 *xbnH=(u16*)alloc(NX*2),  *xbnL=(u16*)alloc(NX*2);
  u16 *c1wH=(u16*)alloc(NC1W*2),*c1wL=(u16*)alloc(NC1W*2);
  u16 *c1oH=(u16*)alloc(NC1O*2),*c1oL=(u16*)alloc(NC1O*2);
  u16 *c2wH=(u16*)alloc(NC2W*2),*c2wL=(u16*)alloc(NC2W*2);
  u16 *c2oH=(u16*)alloc(NC2O*2),*c2oL=(u16*)alloc(NC2O*2);
  u16 *wxH=(u16*)alloc(NWX*2),  *wxL=(u16*)alloc(NWX*2);
  u16 *whH=(u16*)alloc(NWX*2),  *whL=(u16*)alloc(NWX*2);
  float *xbias=(float*)alloc(6*1536*4), *hbias=(float*)alloc(6*1536*4);
  float *xp=(float*)alloc(NXP*4);
  float *yf=(float*)alloc(NC2O*4), *yb=(float*)alloc(NC2O*4);
  u16 *ysH=(u16*)alloc(NC2O*2), *ysL=(u16*)alloc(NC2O*2);
  u16 *fcwH=(u16*)alloc(NFCW*2),*fcwL=(u16*)alloc(NFCW*2);
  float *fcb2=(float*)alloc(512*4);
  u16 *fcoH=(u16*)alloc(NC2O*2),*fcoL=(u16*)alloc(NC2O*2);
  u16 *smwH=(u16*)alloc(NSMW*2),*smwL=(u16*)alloc(NSMW*2);
  u32 *hq=(u32*)alloc(398L*2*8192*4);
  u32 *flags=(u32*)alloc(2*512*4);

  hipMemsetAsync(flags, 0, 2*512*4, stream);

  k_bn1_split<<<8000,256,0,stream>>>(x, bn1g,bn1b,bn1m,bn1v, xbnH,xbnL);
  k_prep_c1w <<<832,256,0,stream>>>(cw0, c1wH,c1wL);
  k_prep_c2w <<<5120,256,0,stream>>>(cw1, c2wH,c2wL);
  k_prep_wx  <<<18432,256,0,stream>>>(gwx, bn2g,bn2v, wxH,wxL);
  k_prep_wh  <<<18432,256,0,stream>>>(gwh, whH,whL);
  k_prep_grub<<<36,256,0,stream>>>(gbia, gwx, bn2g,bn2b,bn2m,bn2v, xbias,hbias);
  k_prep_fcw <<<1024,256,0,stream>>>(fcw, bn3g,bn3v, fcwH,fcwL);
  k_prep_fcb <<<2,256,0,stream>>>(fcw,fcb, bn3g,bn3b,bn3m,bn3v, fcb2);
  k_prep_smw <<<12000,256,0,stream>>>(smw, smwH,smwL);

  // conv1 (now fast path, CW=80): M=12768,N=512,K=416; tiles 100y x 4x = 400
  gemm_lds<80,1><<<400,256,0,stream>>>(xbnH,xbnL, c1wH,c1wL, cb0,
      nullptr, c1oH,c1oL, 12768,512,416, 1600,798, 100, 400);
  // conv2 (CW=512): M=6352,N=512,K=2560; tiles 50y x 4x = 200
  gemm_lds<512,1><<<200,256,0,stream>>>(c1oH,c1oL, c2wH,c2wL, cb1,
      nullptr, c2oH,c2oL, 6352,512,2560, 798,397, 50, 200);

  const u16 *aH = c2oH, *aL = c2oL;
  for (int l = 0; l < 3; ++l){
    // fused xp pair: M=6352, N=3072 (dir0 cols 0-1535, dir1 1536-3071), K=512
    // wx/xbias for both dirs are contiguous at layer base. tiles 50y x 24x = 1200.
    gemm_lds<0,0><<<1200,256,0,stream>>>(aH,aL,
        wxH + (size_t)l*2*786432, wxL + (size_t)l*2*786432,
        xbias + (size_t)l*3072,
        xp, nullptr,nullptr,
        6352,3072,512, 0,0, 50, 1200);
    gru_layer<<<64,256,0,stream>>>(xp,
        whH + (size_t)l*2*786432, whL + (size_t)l*2*786432,
        hbias + l*2*1536, yf,yb, hq, flags, (u32)((l+1)*1000));
    k_sumsplit<<<12704,256,0,stream>>>(yf,yb, ysH,ysL);
    aH = ysH; aL = ysL;
  }

  // fc: M=6352,N=512,K=512; tiles 50y x 4x = 200
  gemm_lds<0,2><<<200,256,0,stream>>>(ysH,ysL, fcwH,fcwL, fcb2,
      nullptr, fcoH,fcoL, 6352,512,512, 0,0, 50, 200);
  // logits: M=6352,N=6000,K=512; tiles 50y x 47x = 2350 -> grid 2352 (div 8)
  gemm_lds<0,0><<<2352,256,0,stream>>>(fcoH,fcoL, smwH,smwL, smb,
      (float*)d_out, nullptr,nullptr, 6352,6000,512, 0,0, 50, 2350);
  k_softmax<<<6352,256,0,stream>>>((float*)d_out);
}